// Round 2
// baseline (349.197 us; speedup 1.0000x reference)
//
#include <hip/hip_runtime.h>
#include <hip/hip_bf16.h>

typedef __hip_bfloat16 bf16;
typedef short bf16x8 __attribute__((ext_vector_type(8)));
typedef float f32x4 __attribute__((ext_vector_type(4)));

#define MFMA16(a,b,c) __builtin_amdgcn_mfma_f32_16x16x32_bf16(a,b,c,0,0,0)

__device__ __forceinline__ unsigned short f2us(float x){
    union{__hip_bfloat16 h; unsigned short u;} c; c.h = __float2bfloat16(x); return c.u;
}
__device__ __forceinline__ float us2f(unsigned short u){
    union{unsigned short u; __hip_bfloat16 h;} c; c.u = u; return __bfloat162float(c.h);
}
__device__ __forceinline__ uint4 pack8(float4 a, float4 b){
    union{unsigned short us[8]; uint4 v;} p;
    p.us[0]=f2us(a.x); p.us[1]=f2us(a.y); p.us[2]=f2us(a.z); p.us[3]=f2us(a.w);
    p.us[4]=f2us(b.x); p.us[5]=f2us(b.y); p.us[6]=f2us(b.z); p.us[7]=f2us(b.w);
    return p.v;
}

// ---------------------------------------------------------------------------
// prep: LDS-tiled transposes (unchanged).
// ---------------------------------------------------------------------------
__global__ __launch_bounds__(256) void prep_kernel(
    const float* __restrict__ Wq, const float* __restrict__ Wk,
    const float* __restrict__ Wv, const float* __restrict__ bq,
    const float* __restrict__ bk, const float* __restrict__ bv,
    const float* __restrict__ Wo,
    bf16* __restrict__ WqT, bf16* __restrict__ WkT, bf16* __restrict__ WvT,
    float* __restrict__ bqp, float* __restrict__ bkp, float* __restrict__ bvp,
    bf16* __restrict__ WoT)
{
    __shared__ float T[64][68];
    const int tid = threadIdx.x, bx = blockIdx.x;
    if (bx < 384) {
        const int mat = bx / 128, rem = bx % 128;
        const int c0 = (rem >> 5) * 64, n0 = (rem & 31) * 64;
        const float* W = (mat == 0) ? Wq : (mat == 1) ? Wk : Wv;
        bf16* WT = (mat == 0) ? WqT : (mat == 1) ? WkT : WvT;
        #pragma unroll
        for (int it = 0; it < 4; ++it) {
            int pp = tid + (it << 8);
            int cl = pp >> 4, n4 = (pp & 15) * 4;
            float4 f = *(const float4*)(W + (size_t)(c0 + cl) * 2048 + n0 + n4);
            T[cl][n4] = f.x; T[cl][n4+1] = f.y; T[cl][n4+2] = f.z; T[cl][n4+3] = f.w;
        }
        __syncthreads();
        const int h = n0 >> 8, d0 = n0 & 255;
        #pragma unroll
        for (int it = 0; it < 2; ++it) {
            int pp = tid + (it << 8);
            int j = pp >> 3, g = pp & 7;
            union{unsigned short us[8]; uint4 v;} pk;
            #pragma unroll
            for (int u = 0; u < 8; ++u) pk.us[u] = f2us(T[g*8+u][j]);
            *(uint4*)(WT + (size_t)((d0 + j) * 8 + h) * 256 + c0 + g * 8) = pk.v;
        }
    } else if (bx < 387) {
        const int mat = bx - 384;
        const float* src = (mat == 0) ? bq : (mat == 1) ? bk : bv;
        float* dst = (mat == 0) ? bqp : (mat == 1) ? bkp : bvp;
        for (int n = tid; n < 2048; n += 256)
            dst[(n & 255) * 8 + (n >> 8)] = src[n];
    } else {
        const int idx = bx - 387;
        const int k0 = (idx >> 2) * 64, c0 = (idx & 3) * 64;
        #pragma unroll
        for (int it = 0; it < 4; ++it) {
            int pp = tid + (it << 8);
            int kl = pp >> 4, c4 = (pp & 15) * 4;
            float4 f = *(const float4*)(Wo + (size_t)(k0 + kl) * 256 + c0 + c4);
            T[kl][c4] = f.x; T[kl][c4+1] = f.y; T[kl][c4+2] = f.z; T[kl][c4+3] = f.w;
        }
        __syncthreads();
        #pragma unroll
        for (int it = 0; it < 2; ++it) {
            int pp = tid + (it << 8);
            int j = pp >> 3, g = pp & 7;
            union{unsigned short us[8]; uint4 v;} pk;
            #pragma unroll
            for (int u = 0; u < 8; ++u) pk.us[u] = f2us(T[g*8+u][j]);
            *(uint4*)(WoT + (size_t)(c0 + j) * 2048 + k0 + g * 8) = pk.v;
        }
    }
}

// ---------------------------------------------------------------------------
// qk v3: 32 tokens/block, 512 threads, grid 512. LDS cut to exactly 80 KiB
// (Xq 16K + Xk 16K + QT 24K + KT 24K) -> 2 blocks/CU -> 4 waves/SIMD.
// Two co-resident blocks have independent barriers, so one block's proj
// MFMAs overlap the other's barrier/L2-load stalls (round-0/1 showed qk is
// latency-bound: all pipes <16% busy at 1 block/CU). Per-token structure
// identical to v2: waves own 32-col slices (nt=0,1), mt halves to 2,
// score pair-MFMA pp2 halves to 2. QT/KT pitch 96B (64B data + quad pad).
// ---------------------------------------------------------------------------
__global__ __launch_bounds__(512, 4) void qk_kernel(
    const float* __restrict__ Qin, const float* __restrict__ Kin,
    const int* __restrict__ mask,
    const bf16* __restrict__ WqT, const bf16* __restrict__ WkT,
    const float* __restrict__ bqp, const float* __restrict__ bkp,
    float* __restrict__ w)
{
    __shared__ __align__(16) char smem[81920];
    char* const Xq = smem;             // [32][256] bf16 swizzled (16 KB)
    char* const Xk = smem + 16384;     // 16 KB
    char* const QT = smem + 32768;     // [256 p2][pitch 96B] (24 KB)
    char* const KT = smem + 57344;     // 24 KB
    float* const RED = (float*)smem;   // [32][68] fp32 alias over Xq

    const int tid  = threadIdx.x;
    const int wid  = tid >> 6, lane = tid & 63;
    const int quad = lane >> 4, l15 = lane & 15;
    const int tok0 = blockIdx.x * 32;

    // stage Xq, Xk once (fp32 -> bf16, XOR-swizzled 16B groups)
    #pragma unroll
    for (int it = 0; it < 2; ++it) {
        int pp = tid + (it << 9);
        int row = pp >> 5, g = pp & 31;
        const float* s = Qin + (size_t)(tok0 + row) * 256 + g * 8;
        *(uint4*)(Xq + row * 512 + ((g ^ (row & 7)) << 4)) =
            pack8(*(const float4*)s, *(const float4*)(s + 4));
        s = Kin + (size_t)(tok0 + row) * 256 + g * 8;
        *(uint4*)(Xk + row * 512 + ((g ^ (row & 7)) << 4)) =
            pack8(*(const float4*)s, *(const float4*)(s + 4));
    }
    __syncthreads();

    f32x4 sacc[2];
    #pragma unroll
    for (int p = 0; p < 2; ++p)
        #pragma unroll
        for (int i = 0; i < 4; ++i) sacc[p][i] = 0.f;

    for (int Cp = 0; Cp < 8; ++Cp) {
        // --- projection: wave computes 32 tokens x 32 cols for Q and K ---
        f32x4 accq[2][2], acck[2][2];
        #pragma unroll
        for (int mt = 0; mt < 2; ++mt)
            #pragma unroll
            for (int nt = 0; nt < 2; ++nt)
                #pragma unroll
                for (int i = 0; i < 4; ++i) { accq[mt][nt][i] = 0.f; acck[mt][nt][i] = 0.f; }
        #pragma unroll
        for (int Ks = 0; Ks < 8; ++Ks) {
            bf16x8 bq[2], bk[2];
            #pragma unroll
            for (int nt = 0; nt < 2; ++nt) {
                const size_t boff =
                    (size_t)(Cp * 256 + wid * 32 + nt * 16 + l15) * 256 + Ks * 32 + quad * 8;
                bq[nt] = *(const bf16x8*)(WqT + boff);
                bk[nt] = *(const bf16x8*)(WkT + boff);
            }
            #pragma unroll
            for (int mt = 0; mt < 2; ++mt) {
                int row = mt * 16 + l15;
                int G = (Ks * 4 + quad) ^ (row & 7);
                bf16x8 aq = *(const bf16x8*)(Xq + row * 512 + (G << 4));
                bf16x8 ak = *(const bf16x8*)(Xk + row * 512 + (G << 4));
                #pragma unroll
                for (int nt = 0; nt < 2; ++nt) {
                    accq[mt][nt] = MFMA16(aq, bq[nt], accq[mt][nt]);
                    acck[mt][nt] = MFMA16(ak, bk[nt], acck[mt][nt]);
                }
            }
        }
        #pragma unroll
        for (int nt = 0; nt < 2; ++nt) {
            const int p2 = wid * 32 + nt * 16 + l15;
            const int rowoff = p2 * 96 + ((p2 >> 6) & 3) * 8;
            const float biq = bqp[Cp * 256 + p2];
            const float bik = bkp[Cp * 256 + p2];
            #pragma unroll
            for (int mt = 0; mt < 2; ++mt) {
                int t0 = mt * 16 + quad * 4;
                union{unsigned short us[4]; uint2 v;} pq, pk;
                #pragma unroll
                for (int i = 0; i < 4; ++i) {
                    pq.us[i] = f2us(accq[mt][nt][i] + biq);
                    pk.us[i] = f2us(acck[mt][nt][i] + bik);
                }
                *(uint2*)(QT + rowoff + t0 * 2) = pq.v;
                *(uint2*)(KT + rowoff + t0 * 2) = pk.v;
            }
        }
        __syncthreads();
        // block-diagonal score MFMA: 2 token-pairs per wave
        #pragma unroll
        for (int pp2 = 0; pp2 < 2; ++pp2) {
            int tq = 2 * (wid * 2 + pp2) + (l15 >> 3);
            union{unsigned short us[8]; bf16x8 v;} Aq, Bk;
            #pragma unroll
            for (int j = 0; j < 8; ++j) {
                int p2 = (quad * 8 + j) * 8 + (l15 & 7);
                int off = p2 * 96 + ((p2 >> 6) & 3) * 8 + tq * 2;
                Aq.us[j] = *(const unsigned short*)(QT + off);
                Bk.us[j] = *(const unsigned short*)(KT + off);
            }
            sacc[pp2] = MFMA16(Aq.v, Bk.v, sacc[pp2]);
        }
        __syncthreads();
    }

    // diagonal extraction -> RED[t][h*8+g]
    if ((quad >> 1) == (l15 >> 3)) {
        #pragma unroll
        for (int pp2 = 0; pp2 < 2; ++pp2) {
            int tl = (wid * 2 + pp2) * 2 + (l15 >> 3);
            #pragma unroll
            for (int i = 0; i < 4; ++i)
                RED[tl * 68 + ((quad & 1) * 4 + i) * 8 + (l15 & 7)] = sacc[pp2][i];
        }
    }
    __syncthreads();
    // softmax: thread (tl, h) -- 32 tokens x 8 heads = first 256 threads
    if (tid < 256) {
        const int tl = tid >> 3, hh = tid & 7;
        const int mk = mask[tok0 + tl];
        const float* r = RED + tl * 68 + hh * 8;
        float m = r[0];
        #pragma unroll
        for (int g = 1; g < 8; ++g) m = fmaxf(m, r[g]);
        float e[8], sum = 0.f;
        #pragma unroll
        for (int g = 0; g < 8; ++g) { e[g] = __expf((r[g] - m) * 0.0625f); sum += e[g]; }
        float inv = 1.f / sum;
        float o[8];
        #pragma unroll
        for (int g = 0; g < 8; ++g) o[g] = mk ? e[g] * inv : 0.125f;
        float* wp = w + (size_t)(tok0 + tl) * 64 + hh * 8;
        *(float4*)wp = make_float4(o[0], o[1], o[2], o[3]);
        *(float4*)(wp + 4) = make_float4(o[4], o[5], o[6], o[7]);
    }
}

// ---------------------------------------------------------------------------
// v_attn: unchanged.
// ---------------------------------------------------------------------------
__global__ __launch_bounds__(512) void v_attn_kernel(
    const float* __restrict__ Vin,
    const bf16* __restrict__ WvT, const float* __restrict__ bvp,
    const float* __restrict__ w, bf16* __restrict__ A)
{
    __shared__ __align__(16) char smem[66560];
    char* const Xv = smem;             // [64][256] bf16 swizzled (32 KB)
    char* const VT = smem + 32768;     // [128 p][pitch 136B] (17408 B)
    char* const xS = smem + 50176;     // [64 t][16 units x 16B swizzled] (16 KB)

    const int tid  = threadIdx.x;
    const int wid  = tid >> 6, lane = tid & 63;
    const int quad = lane >> 4, l15 = lane & 15;
    const int tok0 = blockIdx.x * 64;
    const int t6   = tid & 63, dg = tid >> 6;

    #pragma unroll
    for (int it = 0; it < 4; ++it) {
        int pp = tid + (it << 9);
        int row = pp >> 5, g = pp & 31;
        const float* s = Vin + (size_t)(tok0 + row) * 256 + g * 8;
        *(uint4*)(Xv + row * 512 + ((g ^ (row & 7)) << 4)) =
            pack8(*(const float4*)s, *(const float4*)(s + 4));
    }
    float wv[64];
    {
        const float* wp = w + (size_t)(tok0 + t6) * 64;
        #pragma unroll
        for (int i = 0; i < 16; ++i) {
            float4 f = ((const float4*)wp)[i];
            wv[i*4] = f.x; wv[i*4+1] = f.y; wv[i*4+2] = f.z; wv[i*4+3] = f.w;
        }
    }
    __syncthreads();

    const int pll = wid * 16 + l15;

    for (int C = 0; C < 16; ++C) {
        f32x4 acc[4];
        #pragma unroll
        for (int mt = 0; mt < 4; ++mt)
            #pragma unroll
            for (int i = 0; i < 4; ++i) acc[mt][i] = 0.f;
        #pragma unroll
        for (int Ks = 0; Ks < 8; ++Ks) {
            bf16x8 b = *(const bf16x8*)(WvT + (size_t)(C * 128 + pll) * 256 + Ks * 32 + quad * 8);
            #pragma unroll
            for (int mt = 0; mt < 4; ++mt) {
                int row = mt * 16 + l15;
                int G = (Ks * 4 + quad) ^ (row & 7);
                bf16x8 a = *(const bf16x8*)(Xv + row * 512 + (G << 4));
                acc[mt] = MFMA16(a, b, acc[mt]);
            }
        }
        const float biv = bvp[C * 128 + pll];
        #pragma unroll
        for (int mt = 0; mt < 4; ++mt) {
            int t0 = mt * 16 + quad * 4;
            union{unsigned short us[4]; uint2 v;} pk;
            #pragma unroll
            for (int i = 0; i < 4; ++i) pk.us[i] = f2us(acc[mt][i] + biv);
            *(uint2*)(VT + pll * 136 + t0 * 2) = pk.v;
        }
        __syncthreads();
        // weighted sum: thread (t6, dg) covers d = dg*2 + {0,1}
        #pragma unroll
        for (int dd = 0; dd < 2; ++dd) {
            int d = dg * 2 + dd;
            float vv[8];
            #pragma unroll
            for (int g = 0; g < 8; ++g)
                vv[g] = us2f(*(const unsigned short*)(VT + (d * 8 + g) * 136 + t6 * 2));
            #pragma unroll
            for (int h = 0; h < 8; ++h) {
                float x = 0.f;
                #pragma unroll
                for (int g = 0; g < 8; ++g) x = fmaf(wv[h * 8 + g], vv[g], x);
                int u = (h * 2 + (d >> 3)) ^ (t6 & 15);
                *(unsigned short*)(xS + t6 * 256 + u * 16 + (d & 7) * 2) = f2us(x);
            }
        }
        __syncthreads();
        // scrambled store: thread (t, h) writes 32 B
        {
            int t = tid >> 3, hh = tid & 7;
            int tok = tok0 + t;
            int b = tok >> 11, sr = tok & 2047, sg = sr >> 3, j = sr & 7;
            size_t r = ((size_t)b << 11) + hh * 256 + sg;
            bf16* dst = A + r * 2048 + j * 256 + C * 16;
            int u0 = (hh * 2) ^ (t & 15), u1 = (hh * 2 + 1) ^ (t & 15);
            *(uint4*)dst       = *(const uint4*)(xS + t * 256 + u0 * 16);
            *(uint4*)(dst + 8) = *(const uint4*)(xS + t * 256 + u1 * 16);
        }
    }
}

// ---------------------------------------------------------------------------
// outproj: unchanged.
// ---------------------------------------------------------------------------
__global__ __launch_bounds__(256) void outproj_kernel(
    const bf16* __restrict__ A, const bf16* __restrict__ WoT,
    const float* __restrict__ Wo, const float* __restrict__ bo,
    float* __restrict__ Out)
{
    __shared__ __align__(16) char smem[24576];
    char* const AsS = smem;
    char* const Ws  = smem + 8192;

    const int tid = threadIdx.x;
    const int wave = tid >> 6, lane = tid & 63, quad = lane >> 4, l15 = lane & 15;
    const int R = blockIdx.x >> 1, C = blockIdx.x & 1;
    const int row0 = R * 64, col0 = C * 128;

    f32x4 acc[4][2];
    #pragma unroll
    for (int mt = 0; mt < 4; ++mt)
        #pragma unroll
        for (int nt = 0; nt < 2; ++nt)
            #pragma unroll
            for (int i = 0; i < 4; ++i) acc[mt][nt][i] = 0.f;

    for (int kc = 0; kc < 32; ++kc) {
        __syncthreads();
        #pragma unroll
        for (int it = 0; it < 2; ++it) {
            int pp = tid + (it << 8);
            int rho = pp >> 3, g = pp & 7;
            *(uint4*)(AsS + rho * 128 + ((g ^ (rho & 7)) << 4)) =
                *(const uint4*)(A + (size_t)(row0 + rho) * 2048 + kc * 64 + g * 8);
        }
        if (WoT != nullptr) {
            #pragma unroll
            for (int it = 0; it < 4; ++it) {
                int pp = tid + (it << 8);
                int cl = pp >> 3, g = pp & 7;
                *(uint4*)(Ws + cl * 128 + ((g ^ (cl & 7)) << 4)) =
                    *(const uint4*)(WoT + (size_t)(col0 + cl) * 2048 + kc * 64 + g * 8);
            }
        } else {
            #pragma unroll
            for (int it = 0; it < 8; ++it) {
                int pp = tid + (it << 8);
                int kl = pp >> 5, c4 = (pp & 31) * 4;
                float4 f = *(const float4*)(Wo + (size_t)(kc * 64 + kl) * 256 + col0 + c4);
                float fv[4] = {f.x, f.y, f.z, f.w};
                #pragma unroll
                for (int u = 0; u < 4; ++u) {
                    int cl = c4 + u;
                    *(unsigned short*)(Ws + cl * 128 + (((kl >> 3) ^ (cl & 7)) << 4) + (kl & 7) * 2)
                        = f2us(fv[u]);
                }
            }
        }
        __syncthreads();
        #pragma unroll
        for (int ks = 0; ks < 2; ++ks) {
            bf16x8 a[4], b[2];
            #pragma unroll
            for (int mt = 0; mt < 4; ++mt) {
                int row = mt * 16 + l15;
                int G = (ks * 4 + quad) ^ (row & 7);
                a[mt] = *(const bf16x8*)(AsS + row * 128 + (G << 4));
            }
            #pragma unroll
            for (int nt = 0; nt < 2; ++nt) {
                int cl = wave * 32 + nt * 16 + l15;
                int G = (ks * 4 + quad) ^ (cl & 7);
                b[nt] = *(const bf16x8*)(Ws + cl * 128 + (G << 4));
            }
            #pragma unroll
            for (int mt = 0; mt < 4; ++mt)
                #pragma unroll
                for (int nt = 0; nt < 2; ++nt)
                    acc[mt][nt] = MFMA16(a[mt], b[nt], acc[mt][nt]);
        }
    }
    #pragma unroll
    for (int nt = 0; nt < 2; ++nt) {
        int col = col0 + wave * 32 + nt * 16 + l15;
        float bias = bo[col];
        #pragma unroll
        for (int mt = 0; mt < 4; ++mt) {
            int r0 = row0 + mt * 16 + quad * 4;
            #pragma unroll
            for (int i = 0; i < 4; ++i)
                Out[(size_t)(r0 + i) * 256 + col] = acc[mt][nt][i] + bias;
        }
    }
}

// ---------------------------------------------------------------------------
extern "C" void kernel_launch(void* const* d_in, const int* in_sizes, int n_in,
                              void* d_out, int out_size, void* d_ws, size_t ws_size,
                              hipStream_t stream) {
    const float* query = (const float*)d_in[0];
    const float* key   = (const float*)d_in[1];
    const float* value = (const float*)d_in[2];
    const int*   mask  = (const int*)  d_in[3];
    const float* Wq = (const float*)d_in[4];  const float* bq = (const float*)d_in[5];
    const float* Wk = (const float*)d_in[6];  const float* bk = (const float*)d_in[7];
    const float* Wv = (const float*)d_in[8];  const float* bv = (const float*)d_in[9];
    const float* Wo = (const float*)d_in[10]; const float* bo = (const float*)d_in[11];

    // d_out doubles as scratch; consumed before outproj overwrites d_out.
    char* dc = (char*)d_out;
    bf16*  WqT = (bf16*)dc;                    // [2048][256] bf16, 1 MB
    bf16*  WkT = (bf16*)(dc + 1048576);
    bf16*  WvT = (bf16*)(dc + 2097152);
    float* bqp = (float*)(dc + 3145728);
    float* bkp = (float*)(dc + 3153920);
    float* bvp = (float*)(dc + 3162112);
    float* w   = (float*)(dc + 3170304);       // [16384][64] fp32, 4 MB

    bf16* A = (bf16*)d_ws;                     // scrambled x_att, 64 MB
    const bool big = ws_size >= (67108864ull + 1048576ull);
    bf16* WoT = big ? (bf16*)((char*)d_ws + 67108864) : nullptr;

    prep_kernel<<<big ? 515 : 387, 256, 0, stream>>>(
        Wq, Wk, Wv, bq, bk, bv, Wo, WqT, WkT, WvT, bqp, bkp, bvp, WoT);
    qk_kernel<<<512, 512, 0, stream>>>(
        query, key, mask, WqT, WkT, bqp, bkp, w);
    v_attn_kernel<<<256, 512, 0, stream>>>(value, WvT, bvp, w, A);
    outproj_kernel<<<512, 256, 0, stream>>>(A, WoT, Wo, bo, (float*)d_out);
}

// Round 3
// 328.612 us; speedup vs baseline: 1.0626x; 1.0626x over previous
//
#include <hip/hip_runtime.h>
#include <hip/hip_bf16.h>

typedef __hip_bfloat16 bf16;
typedef short bf16x8 __attribute__((ext_vector_type(8)));
typedef float f32x4 __attribute__((ext_vector_type(4)));

#define MFMA16(a,b,c) __builtin_amdgcn_mfma_f32_16x16x32_bf16(a,b,c,0,0,0)

__device__ __forceinline__ unsigned short f2us(float x){
    union{__hip_bfloat16 h; unsigned short u;} c; c.h = __float2bfloat16(x); return c.u;
}
__device__ __forceinline__ float us2f(unsigned short u){
    union{unsigned short u; __hip_bfloat16 h;} c; c.u = u; return __bfloat162float(c.h);
}
__device__ __forceinline__ uint4 pack8(float4 a, float4 b){
    union{unsigned short us[8]; uint4 v;} p;
    p.us[0]=f2us(a.x); p.us[1]=f2us(a.y); p.us[2]=f2us(a.z); p.us[3]=f2us(a.w);
    p.us[4]=f2us(b.x); p.us[5]=f2us(b.y); p.us[6]=f2us(b.z); p.us[7]=f2us(b.w);
    return p.v;
}

// ---------------------------------------------------------------------------
// prep: LDS-tiled transposes (unchanged).
// ---------------------------------------------------------------------------
__global__ __launch_bounds__(256) void prep_kernel(
    const float* __restrict__ Wq, const float* __restrict__ Wk,
    const float* __restrict__ Wv, const float* __restrict__ bq,
    const float* __restrict__ bk, const float* __restrict__ bv,
    const float* __restrict__ Wo,
    bf16* __restrict__ WqT, bf16* __restrict__ WkT, bf16* __restrict__ WvT,
    float* __restrict__ bqp, float* __restrict__ bkp, float* __restrict__ bvp,
    bf16* __restrict__ WoT)
{
    __shared__ float T[64][68];
    const int tid = threadIdx.x, bx = blockIdx.x;
    if (bx < 384) {
        const int mat = bx / 128, rem = bx % 128;
        const int c0 = (rem >> 5) * 64, n0 = (rem & 31) * 64;
        const float* W = (mat == 0) ? Wq : (mat == 1) ? Wk : Wv;
        bf16* WT = (mat == 0) ? WqT : (mat == 1) ? WkT : WvT;
        #pragma unroll
        for (int it = 0; it < 4; ++it) {
            int pp = tid + (it << 8);
            int cl = pp >> 4, n4 = (pp & 15) * 4;
            float4 f = *(const float4*)(W + (size_t)(c0 + cl) * 2048 + n0 + n4);
            T[cl][n4] = f.x; T[cl][n4+1] = f.y; T[cl][n4+2] = f.z; T[cl][n4+3] = f.w;
        }
        __syncthreads();
        const int h = n0 >> 8, d0 = n0 & 255;
        #pragma unroll
        for (int it = 0; it < 2; ++it) {
            int pp = tid + (it << 8);
            int j = pp >> 3, g = pp & 7;
            union{unsigned short us[8]; uint4 v;} pk;
            #pragma unroll
            for (int u = 0; u < 8; ++u) pk.us[u] = f2us(T[g*8+u][j]);
            *(uint4*)(WT + (size_t)((d0 + j) * 8 + h) * 256 + c0 + g * 8) = pk.v;
        }
    } else if (bx < 387) {
        const int mat = bx - 384;
        const float* src = (mat == 0) ? bq : (mat == 1) ? bk : bv;
        float* dst = (mat == 0) ? bqp : (mat == 1) ? bkp : bvp;
        for (int n = tid; n < 2048; n += 256)
            dst[(n & 255) * 8 + (n >> 8)] = src[n];
    } else {
        const int idx = bx - 387;
        const int k0 = (idx >> 2) * 64, c0 = (idx & 3) * 64;
        #pragma unroll
        for (int it = 0; it < 4; ++it) {
            int pp = tid + (it << 8);
            int kl = pp >> 4, c4 = (pp & 15) * 4;
            float4 f = *(const float4*)(Wo + (size_t)(k0 + kl) * 256 + c0 + c4);
            T[kl][c4] = f.x; T[kl][c4+1] = f.y; T[kl][c4+2] = f.z; T[kl][c4+3] = f.w;
        }
        __syncthreads();
        #pragma unroll
        for (int it = 0; it < 2; ++it) {
            int pp = tid + (it << 8);
            int j = pp >> 3, g = pp & 7;
            union{unsigned short us[8]; uint4 v;} pk;
            #pragma unroll
            for (int u = 0; u < 8; ++u) pk.us[u] = f2us(T[g*8+u][j]);
            *(uint4*)(WoT + (size_t)(c0 + j) * 2048 + k0 + g * 8) = pk.v;
        }
    }
}

// ---------------------------------------------------------------------------
// qk v4: back to 64 tokens/block, grid 256 (round-0 structure, the best),
// plus register software-pipelining of the Cp loop: the next Cp's 32 B-frags
// (128 VGPRs) + bias scalars are loaded right after the current proj phase
// consumes the previous set, giving them the pack/write/barrier/score/barrier
// span (~1500-2000 cy) to cover L2 latency. Cp=0's set hides under staging.
// VGPR budget: LDS caps us at 1 block/CU = 2 waves/SIMD, so up to 256 VGPRs
// are free (__launch_bounds__(512,2)); round-1 proved dropping VGPRs to 64
// for occupancy is a net loss.
// ---------------------------------------------------------------------------
__global__ __launch_bounds__(512, 2) void qk_kernel(
    const float* __restrict__ Qin, const float* __restrict__ Kin,
    const int* __restrict__ mask,
    const bf16* __restrict__ WqT, const bf16* __restrict__ WkT,
    const float* __restrict__ bqp, const float* __restrict__ bkp,
    float* __restrict__ w)
{
    __shared__ __align__(16) char smem[147456];
    char* const Xq = smem;             // [64][256] bf16 swizzled (32 KB)
    char* const Xk = smem + 32768;     // 32 KB
    char* const QT = smem + 65536;     // [256 p2][pitch 160B] (40 KB)
    char* const KT = smem + 106496;    // 40 KB
    float* const RED = (float*)smem;   // [64][68] fp32 alias over Xq

    const int tid  = threadIdx.x;
    const int wid  = tid >> 6, lane = tid & 63;
    const int quad = lane >> 4, l15 = lane & 15;
    const int tok0 = blockIdx.x * 64;

    // stage Xq, Xk once (fp32 -> bf16, XOR-swizzled 16B groups)
    #pragma unroll
    for (int it = 0; it < 4; ++it) {
        int pp = tid + (it << 9);
        int row = pp >> 5, g = pp & 31;
        const float* s = Qin + (size_t)(tok0 + row) * 256 + g * 8;
        *(uint4*)(Xq + row * 512 + ((g ^ (row & 7)) << 4)) =
            pack8(*(const float4*)s, *(const float4*)(s + 4));
        s = Kin + (size_t)(tok0 + row) * 256 + g * 8;
        *(uint4*)(Xk + row * 512 + ((g ^ (row & 7)) << 4)) =
            pack8(*(const float4*)s, *(const float4*)(s + 4));
    }

    // prologue prefetch for Cp=0: 32 B-frags + biases; hides under the
    // staging barrier below.
    bf16x8 pbq[2][8], pbk[2][8];
    float  pbiq[2], pbik[2];
    #pragma unroll
    for (int nt = 0; nt < 2; ++nt) {
        const int p2 = wid * 32 + nt * 16 + l15;
        #pragma unroll
        for (int Ks = 0; Ks < 8; ++Ks) {
            const size_t boff = (size_t)p2 * 256 + Ks * 32 + quad * 8;
            pbq[nt][Ks] = *(const bf16x8*)(WqT + boff);
            pbk[nt][Ks] = *(const bf16x8*)(WkT + boff);
        }
        pbiq[nt] = bqp[p2];
        pbik[nt] = bkp[p2];
    }
    __syncthreads();

    f32x4 sacc[4];
    #pragma unroll
    for (int p = 0; p < 4; ++p)
        #pragma unroll
        for (int i = 0; i < 4; ++i) sacc[p][i] = 0.f;

    for (int Cp = 0; Cp < 8; ++Cp) {
        // --- projection: wave computes 64 tokens x 32 cols for Q and K ---
        f32x4 accq[4][2], acck[4][2];
        #pragma unroll
        for (int mt = 0; mt < 4; ++mt)
            #pragma unroll
            for (int nt = 0; nt < 2; ++nt)
                #pragma unroll
                for (int i = 0; i < 4; ++i) { accq[mt][nt][i] = 0.f; acck[mt][nt][i] = 0.f; }
        #pragma unroll
        for (int Ks = 0; Ks < 8; ++Ks) {
            #pragma unroll
            for (int mt = 0; mt < 4; ++mt) {
                int row = mt * 16 + l15;
                int G = (Ks * 4 + quad) ^ (row & 7);
                bf16x8 aq = *(const bf16x8*)(Xq + row * 512 + (G << 4));
                bf16x8 ak = *(const bf16x8*)(Xk + row * 512 + (G << 4));
                #pragma unroll
                for (int nt = 0; nt < 2; ++nt) {
                    accq[mt][nt] = MFMA16(aq, pbq[nt][Ks], accq[mt][nt]);
                    acck[mt][nt] = MFMA16(ak, pbk[nt][Ks], acck[mt][nt]);
                }
            }
        }
        // save current biases, then prefetch next Cp's B-frags + biases;
        // loads have the rest of this iteration (pack + 2 barriers + score)
        // to complete.
        const float biqc0 = pbiq[0], biqc1 = pbiq[1];
        const float bikc0 = pbik[0], bikc1 = pbik[1];
        if (Cp < 7) {
            const int Cn = Cp + 1;
            #pragma unroll
            for (int nt = 0; nt < 2; ++nt) {
                const int p2 = wid * 32 + nt * 16 + l15;
                #pragma unroll
                for (int Ks = 0; Ks < 8; ++Ks) {
                    const size_t boff =
                        (size_t)(Cn * 256 + p2) * 256 + Ks * 32 + quad * 8;
                    pbq[nt][Ks] = *(const bf16x8*)(WqT + boff);
                    pbk[nt][Ks] = *(const bf16x8*)(WkT + boff);
                }
                pbiq[nt] = bqp[Cn * 256 + p2];
                pbik[nt] = bkp[Cn * 256 + p2];
            }
        }
        #pragma unroll
        for (int nt = 0; nt < 2; ++nt) {
            const int p2 = wid * 32 + nt * 16 + l15;
            const int rowoff = p2 * 160 + ((p2 >> 6) & 3) * 8;
            const float biq = nt ? biqc1 : biqc0;
            const float bik = nt ? bikc1 : bikc0;
            #pragma unroll
            for (int mt = 0; mt < 4; ++mt) {
                int t0 = mt * 16 + quad * 4;
                union{unsigned short us[4]; uint2 v;} pq, pk;
                #pragma unroll
                for (int i = 0; i < 4; ++i) {
                    pq.us[i] = f2us(accq[mt][nt][i] + biq);
                    pk.us[i] = f2us(acck[mt][nt][i] + bik);
                }
                *(uint2*)(QT + rowoff + t0 * 2) = pq.v;
                *(uint2*)(KT + rowoff + t0 * 2) = pk.v;
            }
        }
        __syncthreads();
        // block-diagonal score MFMA: 4 token-pairs per wave
        #pragma unroll
        for (int pp2 = 0; pp2 < 4; ++pp2) {
            int tq = 2 * (wid * 4 + pp2) + (l15 >> 3);
            union{unsigned short us[8]; bf16x8 v;} Aq, Bk;
            #pragma unroll
            for (int j = 0; j < 8; ++j) {
                int p2 = (quad * 8 + j) * 8 + (l15 & 7);
                int off = p2 * 160 + ((p2 >> 6) & 3) * 8 + tq * 2;
                Aq.us[j] = *(const unsigned short*)(QT + off);
                Bk.us[j] = *(const unsigned short*)(KT + off);
            }
            sacc[pp2] = MFMA16(Aq.v, Bk.v, sacc[pp2]);
        }
        __syncthreads();
    }

    // diagonal extraction -> RED[t][h*8+g]
    if ((quad >> 1) == (l15 >> 3)) {
        #pragma unroll
        for (int pp2 = 0; pp2 < 4; ++pp2) {
            int tl = (wid * 4 + pp2) * 2 + (l15 >> 3);
            #pragma unroll
            for (int i = 0; i < 4; ++i)
                RED[tl * 68 + ((quad & 1) * 4 + i) * 8 + (l15 & 7)] = sacc[pp2][i];
        }
    }
    __syncthreads();
    // softmax: thread (tl, h)
    {
        const int tl = tid >> 3, hh = tid & 7;
        const int mk = mask[tok0 + tl];
        const float* r = RED + tl * 68 + hh * 8;
        float m = r[0];
        #pragma unroll
        for (int g = 1; g < 8; ++g) m = fmaxf(m, r[g]);
        float e[8], sum = 0.f;
        #pragma unroll
        for (int g = 0; g < 8; ++g) { e[g] = __expf((r[g] - m) * 0.0625f); sum += e[g]; }
        float inv = 1.f / sum;
        float o[8];
        #pragma unroll
        for (int g = 0; g < 8; ++g) o[g] = mk ? e[g] * inv : 0.125f;
        float* wp = w + (size_t)(tok0 + tl) * 64 + hh * 8;
        *(float4*)wp = make_float4(o[0], o[1], o[2], o[3]);
        *(float4*)(wp + 4) = make_float4(o[4], o[5], o[6], o[7]);
    }
}

// ---------------------------------------------------------------------------
// v_attn: unchanged.
// ---------------------------------------------------------------------------
__global__ __launch_bounds__(512) void v_attn_kernel(
    const float* __restrict__ Vin,
    const bf16* __restrict__ WvT, const float* __restrict__ bvp,
    const float* __restrict__ w, bf16* __restrict__ A)
{
    __shared__ __align__(16) char smem[66560];
    char* const Xv = smem;             // [64][256] bf16 swizzled (32 KB)
    char* const VT = smem + 32768;     // [128 p][pitch 136B] (17408 B)
    char* const xS = smem + 50176;     // [64 t][16 units x 16B swizzled] (16 KB)

    const int tid  = threadIdx.x;
    const int wid  = tid >> 6, lane = tid & 63;
    const int quad = lane >> 4, l15 = lane & 15;
    const int tok0 = blockIdx.x * 64;
    const int t6   = tid & 63, dg = tid >> 6;

    #pragma unroll
    for (int it = 0; it < 4; ++it) {
        int pp = tid + (it << 9);
        int row = pp >> 5, g = pp & 31;
        const float* s = Vin + (size_t)(tok0 + row) * 256 + g * 8;
        *(uint4*)(Xv + row * 512 + ((g ^ (row & 7)) << 4)) =
            pack8(*(const float4*)s, *(const float4*)(s + 4));
    }
    float wv[64];
    {
        const float* wp = w + (size_t)(tok0 + t6) * 64;
        #pragma unroll
        for (int i = 0; i < 16; ++i) {
            float4 f = ((const float4*)wp)[i];
            wv[i*4] = f.x; wv[i*4+1] = f.y; wv[i*4+2] = f.z; wv[i*4+3] = f.w;
        }
    }
    __syncthreads();

    const int pll = wid * 16 + l15;

    for (int C = 0; C < 16; ++C) {
        f32x4 acc[4];
        #pragma unroll
        for (int mt = 0; mt < 4; ++mt)
            #pragma unroll
            for (int i = 0; i < 4; ++i) acc[mt][i] = 0.f;
        #pragma unroll
        for (int Ks = 0; Ks < 8; ++Ks) {
            bf16x8 b = *(const bf16x8*)(WvT + (size_t)(C * 128 + pll) * 256 + Ks * 32 + quad * 8);
            #pragma unroll
            for (int mt = 0; mt < 4; ++mt) {
                int row = mt * 16 + l15;
                int G = (Ks * 4 + quad) ^ (row & 7);
                bf16x8 a = *(const bf16x8*)(Xv + row * 512 + (G << 4));
                acc[mt] = MFMA16(a, b, acc[mt]);
            }
        }
        const float biv = bvp[C * 128 + pll];
        #pragma unroll
        for (int mt = 0; mt < 4; ++mt) {
            int t0 = mt * 16 + quad * 4;
            union{unsigned short us[4]; uint2 v;} pk;
            #pragma unroll
            for (int i = 0; i < 4; ++i) pk.us[i] = f2us(acc[mt][i] + biv);
            *(uint2*)(VT + pll * 136 + t0 * 2) = pk.v;
        }
        __syncthreads();
        // weighted sum: thread (t6, dg) covers d = dg*2 + {0,1}
        #pragma unroll
        for (int dd = 0; dd < 2; ++dd) {
            int d = dg * 2 + dd;
            float vv[8];
            #pragma unroll
            for (int g = 0; g < 8; ++g)
                vv[g] = us2f(*(const unsigned short*)(VT + (d * 8 + g) * 136 + t6 * 2));
            #pragma unroll
            for (int h = 0; h < 8; ++h) {
                float x = 0.f;
                #pragma unroll
                for (int g = 0; g < 8; ++g) x = fmaf(wv[h * 8 + g], vv[g], x);
                int u = (h * 2 + (d >> 3)) ^ (t6 & 15);
                *(unsigned short*)(xS + t6 * 256 + u * 16 + (d & 7) * 2) = f2us(x);
            }
        }
        __syncthreads();
        // scrambled store: thread (t, h) writes 32 B
        {
            int t = tid >> 3, hh = tid & 7;
            int tok = tok0 + t;
            int b = tok >> 11, sr = tok & 2047, sg = sr >> 3, j = sr & 7;
            size_t r = ((size_t)b << 11) + hh * 256 + sg;
            bf16* dst = A + r * 2048 + j * 256 + C * 16;
            int u0 = (hh * 2) ^ (t & 15), u1 = (hh * 2 + 1) ^ (t & 15);
            *(uint4*)dst       = *(const uint4*)(xS + t * 256 + u0 * 16);
            *(uint4*)(dst + 8) = *(const uint4*)(xS + t * 256 + u1 * 16);
        }
    }
}

// ---------------------------------------------------------------------------
// outproj: unchanged.
// ---------------------------------------------------------------------------
__global__ __launch_bounds__(256) void outproj_kernel(
    const bf16* __restrict__ A, const bf16* __restrict__ WoT,
    const float* __restrict__ Wo, const float* __restrict__ bo,
    float* __restrict__ Out)
{
    __shared__ __align__(16) char smem[24576];
    char* const AsS = smem;
    char* const Ws  = smem + 8192;

    const int tid = threadIdx.x;
    const int wave = tid >> 6, lane = tid & 63, quad = lane >> 4, l15 = lane & 15;
    const int R = blockIdx.x >> 1, C = blockIdx.x & 1;
    const int row0 = R * 64, col0 = C * 128;

    f32x4 acc[4][2];
    #pragma unroll
    for (int mt = 0; mt < 4; ++mt)
        #pragma unroll
        for (int nt = 0; nt < 2; ++nt)
            #pragma unroll
            for (int i = 0; i < 4; ++i) acc[mt][nt][i] = 0.f;

    for (int kc = 0; kc < 32; ++kc) {
        __syncthreads();
        #pragma unroll
        for (int it = 0; it < 2; ++it) {
            int pp = tid + (it << 8);
            int rho = pp >> 3, g = pp & 7;
            *(uint4*)(AsS + rho * 128 + ((g ^ (rho & 7)) << 4)) =
                *(const uint4*)(A + (size_t)(row0 + rho) * 2048 + kc * 64 + g * 8);
        }
        if (WoT != nullptr) {
            #pragma unroll
            for (int it = 0; it < 4; ++it) {
                int pp = tid + (it << 8);
                int cl = pp >> 3, g = pp & 7;
                *(uint4*)(Ws + cl * 128 + ((g ^ (cl & 7)) << 4)) =
                    *(const uint4*)(WoT + (size_t)(col0 + cl) * 2048 + kc * 64 + g * 8);
            }
        } else {
            #pragma unroll
            for (int it = 0; it < 8; ++it) {
                int pp = tid + (it << 8);
                int kl = pp >> 5, c4 = (pp & 31) * 4;
                float4 f = *(const float4*)(Wo + (size_t)(kc * 64 + kl) * 256 + col0 + c4);
                float fv[4] = {f.x, f.y, f.z, f.w};
                #pragma unroll
                for (int u = 0; u < 4; ++u) {
                    int cl = c4 + u;
                    *(unsigned short*)(Ws + cl * 128 + (((kl >> 3) ^ (cl & 7)) << 4) + (kl & 7) * 2)
                        = f2us(fv[u]);
                }
            }
        }
        __syncthreads();
        #pragma unroll
        for (int ks = 0; ks < 2; ++ks) {
            bf16x8 a[4], b[2];
            #pragma unroll
            for (int mt = 0; mt < 4; ++mt) {
                int row = mt * 16 + l15;
                int G = (ks * 4 + quad) ^ (row & 7);
                a[mt] = *(const bf16x8*)(AsS + row * 128 + (G << 4));
            }
            #pragma unroll
            for (int nt = 0; nt < 2; ++nt) {
                int cl = wave * 32 + nt * 16 + l15;
                int G = (ks * 4 + quad) ^ (cl & 7);
                b[nt] = *(const bf16x8*)(Ws + cl * 128 + (G << 4));
            }
            #pragma unroll
            for (int mt = 0; mt < 4; ++mt)
                #pragma unroll
                for (int nt = 0; nt < 2; ++nt)
                    acc[mt][nt] = MFMA16(a[mt], b[nt], acc[mt][nt]);
        }
    }
    #pragma unroll
    for (int nt = 0; nt < 2; ++nt) {
        int col = col0 + wave * 32 + nt * 16 + l15;
        float bias = bo[col];
        #pragma unroll
        for (int mt = 0; mt < 4; ++mt) {
            int r0 = row0 + mt * 16 + quad * 4;
            #pragma unroll
            for (int i = 0; i < 4; ++i)
                Out[(size_t)(r0 + i) * 256 + col] = acc[mt][nt][i] + bias;
        }
    }
}

// ---------------------------------------------------------------------------
extern "C" void kernel_launch(void* const* d_in, const int* in_sizes, int n_in,
                              void* d_out, int out_size, void* d_ws, size_t ws_size,
                              hipStream_t stream) {
    const float* query = (const float*)d_in[0];
    const float* key   = (const float*)d_in[1];
    const float* value = (const float*)d_in[2];
    const int*   mask  = (const int*)  d_in[3];
    const float* Wq = (const float*)d_in[4];  const float* bq = (const float*)d_in[5];
    const float* Wk = (const float*)d_in[6];  const float* bk = (const float*)d_in[7];
    const float* Wv = (const float*)d_in[8];  const float* bv = (const float*)d_in[9];
    const float* Wo = (const float*)d_in[10]; const float* bo = (const float*)d_in[11];

    // d_out doubles as scratch; consumed before outproj overwrites d_out.
    char* dc = (char*)d_out;
    bf16*  WqT = (bf16*)dc;                    // [2048][256] bf16, 1 MB
    bf16*  WkT = (bf16*)(dc + 1048576);
    bf16*  WvT = (bf16*)(dc + 2097152);
    float* bqp = (float*)(dc + 3145728);
    float* bkp = (float*)(dc + 3153920);
    float* bvp = (float*)(dc + 3162112);
    float* w   = (float*)(dc + 3170304);       // [16384][64] fp32, 4 MB

    bf16* A = (bf16*)d_ws;                     // scrambled x_att, 64 MB
    const bool big = ws_size >= (67108864ull + 1048576ull);
    bf16* WoT = big ? (bf16*)((char*)d_ws + 67108864) : nullptr;

    prep_kernel<<<big ? 515 : 387, 256, 0, stream>>>(
        Wq, Wk, Wv, bq, bk, bv, Wo, WqT, WkT, WvT, bqp, bkp, bvp, WoT);
    qk_kernel<<<256, 512, 0, stream>>>(
        query, key, mask, WqT, WkT, bqp, bkp, w);
    v_attn_kernel<<<256, 512, 0, stream>>>(value, WvT, bvp, w, A);
    outproj_kernel<<<512, 256, 0, stream>>>(A, WoT, Wo, bo, (float*)d_out);
}

// Round 4
// 272.968 us; speedup vs baseline: 1.2793x; 1.2038x over previous
//
#include <hip/hip_runtime.h>
#include <hip/hip_bf16.h>

typedef __hip_bfloat16 bf16;
typedef short bf16x8 __attribute__((ext_vector_type(8)));
typedef float f32x4 __attribute__((ext_vector_type(4)));

#define MFMA16(a,b,c) __builtin_amdgcn_mfma_f32_16x16x32_bf16(a,b,c,0,0,0)

__device__ __forceinline__ unsigned short f2us(float x){
    union{__hip_bfloat16 h; unsigned short u;} c; c.h = __float2bfloat16(x); return c.u;
}
__device__ __forceinline__ float us2f(unsigned short u){
    union{unsigned short u; __hip_bfloat16 h;} c; c.u = u; return __bfloat162float(c.h);
}
__device__ __forceinline__ uint4 pack8(float4 a, float4 b){
    union{unsigned short us[8]; uint4 v;} p;
    p.us[0]=f2us(a.x); p.us[1]=f2us(a.y); p.us[2]=f2us(a.z); p.us[3]=f2us(a.w);
    p.us[4]=f2us(b.x); p.us[5]=f2us(b.y); p.us[6]=f2us(b.z); p.us[7]=f2us(b.w);
    return p.v;
}

// ---------------------------------------------------------------------------
// prep: LDS-tiled transposes (unchanged; WoT now always produced).
// ---------------------------------------------------------------------------
__global__ __launch_bounds__(256) void prep_kernel(
    const float* __restrict__ Wq, const float* __restrict__ Wk,
    const float* __restrict__ Wv, const float* __restrict__ bq,
    const float* __restrict__ bk, const float* __restrict__ bv,
    const float* __restrict__ Wo,
    bf16* __restrict__ WqT, bf16* __restrict__ WkT, bf16* __restrict__ WvT,
    float* __restrict__ bqp, float* __restrict__ bkp, float* __restrict__ bvp,
    bf16* __restrict__ WoT)
{
    __shared__ float T[64][68];
    const int tid = threadIdx.x, bx = blockIdx.x;
    if (bx < 384) {
        const int mat = bx / 128, rem = bx % 128;
        const int c0 = (rem >> 5) * 64, n0 = (rem & 31) * 64;
        const float* W = (mat == 0) ? Wq : (mat == 1) ? Wk : Wv;
        bf16* WT = (mat == 0) ? WqT : (mat == 1) ? WkT : WvT;
        #pragma unroll
        for (int it = 0; it < 4; ++it) {
            int pp = tid + (it << 8);
            int cl = pp >> 4, n4 = (pp & 15) * 4;
            float4 f = *(const float4*)(W + (size_t)(c0 + cl) * 2048 + n0 + n4);
            T[cl][n4] = f.x; T[cl][n4+1] = f.y; T[cl][n4+2] = f.z; T[cl][n4+3] = f.w;
        }
        __syncthreads();
        const int h = n0 >> 8, d0 = n0 & 255;
        #pragma unroll
        for (int it = 0; it < 2; ++it) {
            int pp = tid + (it << 8);
            int j = pp >> 3, g = pp & 7;
            union{unsigned short us[8]; uint4 v;} pk;
            #pragma unroll
            for (int u = 0; u < 8; ++u) pk.us[u] = f2us(T[g*8+u][j]);
            *(uint4*)(WT + (size_t)((d0 + j) * 8 + h) * 256 + c0 + g * 8) = pk.v;
        }
    } else if (bx < 387) {
        const int mat = bx - 384;
        const float* src = (mat == 0) ? bq : (mat == 1) ? bk : bv;
        float* dst = (mat == 0) ? bqp : (mat == 1) ? bkp : bvp;
        for (int n = tid; n < 2048; n += 256)
            dst[(n & 255) * 8 + (n >> 8)] = src[n];
    } else {
        const int idx = bx - 387;
        const int k0 = (idx >> 2) * 64, c0 = (idx & 3) * 64;
        #pragma unroll
        for (int it = 0; it < 4; ++it) {
            int pp = tid + (it << 8);
            int kl = pp >> 4, c4 = (pp & 15) * 4;
            float4 f = *(const float4*)(Wo + (size_t)(k0 + kl) * 256 + c0 + c4);
            T[kl][c4] = f.x; T[kl][c4+1] = f.y; T[kl][c4+2] = f.z; T[kl][c4+3] = f.w;
        }
        __syncthreads();
        #pragma unroll
        for (int it = 0; it < 2; ++it) {
            int pp = tid + (it << 8);
            int j = pp >> 3, g = pp & 7;
            union{unsigned short us[8]; uint4 v;} pk;
            #pragma unroll
            for (int u = 0; u < 8; ++u) pk.us[u] = f2us(T[g*8+u][j]);
            *(uint4*)(WoT + (size_t)(c0 + j) * 2048 + k0 + g * 8) = pk.v;
        }
    }
}

// ---------------------------------------------------------------------------
// qk: exact round-0 structure (93.7 us measured): 64 tokens/block, grid 256,
// waves own 32-col slices (nt=0,1), direct-global B-frags, QT/KT round-trip,
// block-diagonal pair-MFMA scores, softmax -> w. Only pointer bases changed
// (scratch now lives in d_ws).
// ---------------------------------------------------------------------------
__global__ __launch_bounds__(512, 2) void qk_kernel(
    const float* __restrict__ Qin, const float* __restrict__ Kin,
    const int* __restrict__ mask,
    const bf16* __restrict__ WqT, const bf16* __restrict__ WkT,
    const float* __restrict__ bqp, const float* __restrict__ bkp,
    float* __restrict__ w)
{
    __shared__ __align__(16) char smem[147456];
    char* const Xq = smem;             // [64][256] bf16 swizzled (32 KB)
    char* const Xk = smem + 32768;     // 32 KB
    char* const QT = smem + 65536;     // [256 p2][pitch 160B] (40 KB)
    char* const KT = smem + 106496;    // 40 KB
    float* const RED = (float*)smem;   // [64][68] fp32 alias over Xq

    const int tid  = threadIdx.x;
    const int wid  = tid >> 6, lane = tid & 63;
    const int quad = lane >> 4, l15 = lane & 15;
    const int tok0 = blockIdx.x * 64;

    #pragma unroll
    for (int it = 0; it < 4; ++it) {
        int pp = tid + (it << 9);
        int row = pp >> 5, g = pp & 31;
        const float* s = Qin + (size_t)(tok0 + row) * 256 + g * 8;
        *(uint4*)(Xq + row * 512 + ((g ^ (row & 7)) << 4)) =
            pack8(*(const float4*)s, *(const float4*)(s + 4));
        s = Kin + (size_t)(tok0 + row) * 256 + g * 8;
        *(uint4*)(Xk + row * 512 + ((g ^ (row & 7)) << 4)) =
            pack8(*(const float4*)s, *(const float4*)(s + 4));
    }
    __syncthreads();

    f32x4 sacc[4];
    #pragma unroll
    for (int p = 0; p < 4; ++p)
        #pragma unroll
        for (int i = 0; i < 4; ++i) sacc[p][i] = 0.f;

    for (int Cp = 0; Cp < 8; ++Cp) {
        f32x4 accq[4][2], acck[4][2];
        #pragma unroll
        for (int mt = 0; mt < 4; ++mt)
            #pragma unroll
            for (int nt = 0; nt < 2; ++nt)
                #pragma unroll
                for (int i = 0; i < 4; ++i) { accq[mt][nt][i] = 0.f; acck[mt][nt][i] = 0.f; }
        #pragma unroll
        for (int Ks = 0; Ks < 8; ++Ks) {
            bf16x8 bq[2], bk[2];
            #pragma unroll
            for (int nt = 0; nt < 2; ++nt) {
                const size_t boff =
                    (size_t)(Cp * 256 + wid * 32 + nt * 16 + l15) * 256 + Ks * 32 + quad * 8;
                bq[nt] = *(const bf16x8*)(WqT + boff);
                bk[nt] = *(const bf16x8*)(WkT + boff);
            }
            #pragma unroll
            for (int mt = 0; mt < 4; ++mt) {
                int row = mt * 16 + l15;
                int G = (Ks * 4 + quad) ^ (row & 7);
                bf16x8 aq = *(const bf16x8*)(Xq + row * 512 + (G << 4));
                bf16x8 ak = *(const bf16x8*)(Xk + row * 512 + (G << 4));
                #pragma unroll
                for (int nt = 0; nt < 2; ++nt) {
                    accq[mt][nt] = MFMA16(aq, bq[nt], accq[mt][nt]);
                    acck[mt][nt] = MFMA16(ak, bk[nt], acck[mt][nt]);
                }
            }
        }
        #pragma unroll
        for (int nt = 0; nt < 2; ++nt) {
            const int p2 = wid * 32 + nt * 16 + l15;
            const int rowoff = p2 * 160 + ((p2 >> 6) & 3) * 8;
            const float biq = bqp[Cp * 256 + p2];
            const float bik = bkp[Cp * 256 + p2];
            #pragma unroll
            for (int mt = 0; mt < 4; ++mt) {
                int t0 = mt * 16 + quad * 4;
                union{unsigned short us[4]; uint2 v;} pq, pk;
                #pragma unroll
                for (int i = 0; i < 4; ++i) {
                    pq.us[i] = f2us(accq[mt][nt][i] + biq);
                    pk.us[i] = f2us(acck[mt][nt][i] + bik);
                }
                *(uint2*)(QT + rowoff + t0 * 2) = pq.v;
                *(uint2*)(KT + rowoff + t0 * 2) = pk.v;
            }
        }
        __syncthreads();
        #pragma unroll
        for (int pp2 = 0; pp2 < 4; ++pp2) {
            int tq = 2 * (wid * 4 + pp2) + (l15 >> 3);
            union{unsigned short us[8]; bf16x8 v;} Aq, Bk;
            #pragma unroll
            for (int j = 0; j < 8; ++j) {
                int p2 = (quad * 8 + j) * 8 + (l15 & 7);
                int off = p2 * 160 + ((p2 >> 6) & 3) * 8 + tq * 2;
                Aq.us[j] = *(const unsigned short*)(QT + off);
                Bk.us[j] = *(const unsigned short*)(KT + off);
            }
            sacc[pp2] = MFMA16(Aq.v, Bk.v, sacc[pp2]);
        }
        __syncthreads();
    }

    if ((quad >> 1) == (l15 >> 3)) {
        #pragma unroll
        for (int pp2 = 0; pp2 < 4; ++pp2) {
            int tl = (wid * 4 + pp2) * 2 + (l15 >> 3);
            #pragma unroll
            for (int i = 0; i < 4; ++i)
                RED[tl * 68 + ((quad & 1) * 4 + i) * 8 + (l15 & 7)] = sacc[pp2][i];
        }
    }
    __syncthreads();
    {
        const int tl = tid >> 3, hh = tid & 7;
        const int mk = mask[tok0 + tl];
        const float* r = RED + tl * 68 + hh * 8;
        float m = r[0];
        #pragma unroll
        for (int g = 1; g < 8; ++g) m = fmaxf(m, r[g]);
        float e[8], sum = 0.f;
        #pragma unroll
        for (int g = 0; g < 8; ++g) { e[g] = __expf((r[g] - m) * 0.0625f); sum += e[g]; }
        float inv = 1.f / sum;
        float o[8];
        #pragma unroll
        for (int g = 0; g < 8; ++g) o[g] = mk ? e[g] * inv : 0.125f;
        float* wp = w + (size_t)(tok0 + tl) * 64 + hh * 8;
        *(float4*)wp = make_float4(o[0], o[1], o[2], o[3]);
        *(float4*)(wp + 4) = make_float4(o[4], o[5], o[6], o[7]);
    }
}

// ---------------------------------------------------------------------------
// av: fused v_attn + outproj. 64 tokens/block, 512 threads, grid 256.
// Per C chunk: v-proj -> VT -> weighted sum -> xS (all as before), then
// instead of a scrambled global store of xatt, MFMA-accumulate the block's
// 64x256 output tile in registers against WoT rows k = j*256 + C*16 + u.
// After the C loop: add bo, write Out directly. The 64 MB A buffer, its
// 128 MB HBM round-trip, and the outproj kernel are eliminated.
// Out rows for this block: r = (b<<11) + h*256 + sg0 + sgl  (the reference's
// transpose-reshape row scramble), rr_local = h*8+sgl in [0,64).
// ---------------------------------------------------------------------------
__global__ __launch_bounds__(512, 2) void av_kernel(
    const float* __restrict__ Vin,
    const bf16* __restrict__ WvT, const float* __restrict__ bvp,
    const float* __restrict__ w, const bf16* __restrict__ WoT,
    const float* __restrict__ bo, float* __restrict__ Out)
{
    __shared__ __align__(16) char smem[66560];
    char* const Xv = smem;             // [64][256] bf16 swizzled (32 KB)
    char* const VT = smem + 32768;     // [128 p][pitch 136B] (17408 B)
    char* const xS = smem + 50176;     // [64 t][16 units x 16B swizzled] (16 KB)

    const int tid  = threadIdx.x;
    const int wid  = tid >> 6, lane = tid & 63;
    const int quad = lane >> 4, l15 = lane & 15;
    const int tok0 = blockIdx.x * 64;
    const int t6   = tid & 63, dg = tid >> 6;

    #pragma unroll
    for (int it = 0; it < 4; ++it) {
        int pp = tid + (it << 9);
        int row = pp >> 5, g = pp & 31;
        const float* s = Vin + (size_t)(tok0 + row) * 256 + g * 8;
        *(uint4*)(Xv + row * 512 + ((g ^ (row & 7)) << 4)) =
            pack8(*(const float4*)s, *(const float4*)(s + 4));
    }
    float wv[64];
    {
        const float* wp = w + (size_t)(tok0 + t6) * 64;
        #pragma unroll
        for (int i = 0; i < 16; ++i) {
            float4 f = ((const float4*)wp)[i];
            wv[i*4] = f.x; wv[i*4+1] = f.y; wv[i*4+2] = f.z; wv[i*4+3] = f.w;
        }
    }
    __syncthreads();

    const int pll = wid * 16 + l15;

    // output accumulator: rows rr = mt*16 + quad*4 + i (rr = h*8+sgl),
    // cols c = wid*32 + nt*16 + l15
    f32x4 oacc[4][2];
    #pragma unroll
    for (int mt = 0; mt < 4; ++mt)
        #pragma unroll
        for (int nt = 0; nt < 2; ++nt)
            #pragma unroll
            for (int i = 0; i < 4; ++i) oacc[mt][nt][i] = 0.f;

    for (int C = 0; C < 16; ++C) {
        // --- v-proj for cols C*128..C*128+127 in p=(d*8+h) layout ---
        f32x4 acc[4];
        #pragma unroll
        for (int mt = 0; mt < 4; ++mt)
            #pragma unroll
            for (int i = 0; i < 4; ++i) acc[mt][i] = 0.f;
        #pragma unroll
        for (int Ks = 0; Ks < 8; ++Ks) {
            bf16x8 b = *(const bf16x8*)(WvT + (size_t)(C * 128 + pll) * 256 + Ks * 32 + quad * 8);
            #pragma unroll
            for (int mt = 0; mt < 4; ++mt) {
                int row = mt * 16 + l15;
                int G = (Ks * 4 + quad) ^ (row & 7);
                bf16x8 a = *(const bf16x8*)(Xv + row * 512 + (G << 4));
                acc[mt] = MFMA16(a, b, acc[mt]);
            }
        }
        const float biv = bvp[C * 128 + pll];
        #pragma unroll
        for (int mt = 0; mt < 4; ++mt) {
            int t0 = mt * 16 + quad * 4;
            union{unsigned short us[4]; uint2 v;} pk;
            #pragma unroll
            for (int i = 0; i < 4; ++i) pk.us[i] = f2us(acc[mt][i] + biv);
            *(uint2*)(VT + pll * 136 + t0 * 2) = pk.v;
        }
        __syncthreads();
        // --- weighted sum: thread (t6, dg) covers local d = dg*2 + {0,1} ---
        #pragma unroll
        for (int dd = 0; dd < 2; ++dd) {
            int d = dg * 2 + dd;
            float vv[8];
            #pragma unroll
            for (int g = 0; g < 8; ++g)
                vv[g] = us2f(*(const unsigned short*)(VT + (d * 8 + g) * 136 + t6 * 2));
            #pragma unroll
            for (int h = 0; h < 8; ++h) {
                float x = 0.f;
                #pragma unroll
                for (int g = 0; g < 8; ++g) x = fmaf(wv[h * 8 + g], vv[g], x);
                int u = (h * 2 + (d >> 3)) ^ (t6 & 15);
                *(unsigned short*)(xS + t6 * 256 + u * 16 + (d & 7) * 2) = f2us(x);
            }
        }
        __syncthreads();
        // --- out-proj accumulate: K=128 slice (k = j*256 + C*16 + u) ---
        #pragma unroll
        for (int m = 0; m < 4; ++m) {
            const int j  = 2 * m + (quad >> 1);
            const int k0 = j * 256 + C * 16 + (quad & 1) * 8;
            bf16x8 bfr[2];
            #pragma unroll
            for (int nt = 0; nt < 2; ++nt) {
                int c = wid * 32 + nt * 16 + l15;
                bfr[nt] = *(const bf16x8*)(WoT + (size_t)c * 2048 + k0);
            }
            #pragma unroll
            for (int mt = 0; mt < 4; ++mt) {
                int h = mt * 2 + (l15 >> 3);
                int t = (l15 & 7) * 8 + j;
                int u = (h * 2 + (quad & 1)) ^ (t & 15);
                bf16x8 afr = *(const bf16x8*)(xS + t * 256 + u * 16);
                #pragma unroll
                for (int nt = 0; nt < 2; ++nt)
                    oacc[mt][nt] = MFMA16(afr, bfr[nt], oacc[mt][nt]);
            }
        }
        // next C's v-proj only writes VT (last read before barrier 2);
        // xS next written after the following barrier 1 -> no extra barrier.
    }

    // epilogue: bias + direct Out write in the reference's scrambled row order
    const int b = tok0 >> 11, sg0 = (tok0 & 2047) >> 3;
    #pragma unroll
    for (int nt = 0; nt < 2; ++nt) {
        int c = wid * 32 + nt * 16 + l15;
        float bias = bo[c];
        #pragma unroll
        for (int mt = 0; mt < 4; ++mt) {
            #pragma unroll
            for (int i = 0; i < 4; ++i) {
                int rr = mt * 16 + quad * 4 + i;
                int h = rr >> 3, sgl = rr & 7;
                size_t r = ((size_t)b << 11) + h * 256 + sg0 + sgl;
                Out[r * 256 + c] = oacc[mt][nt][i] + bias;
            }
        }
    }
}

// ---------------------------------------------------------------------------
extern "C" void kernel_launch(void* const* d_in, const int* in_sizes, int n_in,
                              void* d_out, int out_size, void* d_ws, size_t ws_size,
                              hipStream_t stream) {
    const float* query = (const float*)d_in[0];
    const float* key   = (const float*)d_in[1];
    const float* value = (const float*)d_in[2];
    const int*   mask  = (const int*)  d_in[3];
    const float* Wq = (const float*)d_in[4];  const float* bq = (const float*)d_in[5];
    const float* Wk = (const float*)d_in[6];  const float* bk = (const float*)d_in[7];
    const float* Wv = (const float*)d_in[8];  const float* bv = (const float*)d_in[9];
    const float* Wo = (const float*)d_in[10]; const float* bo = (const float*)d_in[11];

    // all scratch in d_ws (d_out is now written directly by av_kernel):
    char* ws = (char*)d_ws;
    bf16*  WoT = (bf16*)ws;                    // [256 c][2048 k] bf16, 1 MB
    bf16*  WqT = (bf16*)(ws + 1048576);        // [2048][256] bf16, 1 MB each
    bf16*  WkT = (bf16*)(ws + 2097152);
    bf16*  WvT = (bf16*)(ws + 3145728);
    float* bqp = (float*)(ws + 4194304);
    float* bkp = (float*)(ws + 4202496);
    float* bvp = (float*)(ws + 4210688);
    float* w   = (float*)(ws + 4218880);       // [16384][64] fp32, 4 MB

    prep_kernel<<<515, 256, 0, stream>>>(
        Wq, Wk, Wv, bq, bk, bv, Wo, WqT, WkT, WvT, bqp, bkp, bvp, WoT);
    qk_kernel<<<256, 512, 0, stream>>>(
        query, key, mask, WqT, WkT, bqp, bkp, w);
    av_kernel<<<256, 512, 0, stream>>>(
        value, WvT, bvp, w, WoT, bo, (float*)d_out);
}

// Round 5
// 268.838 us; speedup vs baseline: 1.2989x; 1.0154x over previous
//
#include <hip/hip_runtime.h>
#include <hip/hip_bf16.h>

typedef __hip_bfloat16 bf16;
typedef short bf16x8 __attribute__((ext_vector_type(8)));
typedef float f32x4 __attribute__((ext_vector_type(4)));

#define MFMA16(a,b,c) __builtin_amdgcn_mfma_f32_16x16x32_bf16(a,b,c,0,0,0)

__device__ __forceinline__ unsigned short f2us(float x){
    union{__hip_bfloat16 h; unsigned short u;} c; c.h = __float2bfloat16(x); return c.u;
}
__device__ __forceinline__ float us2f(unsigned short u){
    union{unsigned short u; __hip_bfloat16 h;} c; c.u = u; return __bfloat162float(c.h);
}
__device__ __forceinline__ uint4 pack8(float4 a, float4 b){
    union{unsigned short us[8]; uint4 v;} p;
    p.us[0]=f2us(a.x); p.us[1]=f2us(a.y); p.us[2]=f2us(a.z); p.us[3]=f2us(a.w);
    p.us[4]=f2us(b.x); p.us[5]=f2us(b.y); p.us[6]=f2us(b.z); p.us[7]=f2us(b.w);
    return p.v;
}

// ---------------------------------------------------------------------------
// prep: LDS-tiled transposes (unchanged).
// ---------------------------------------------------------------------------
__global__ __launch_bounds__(256) void prep_kernel(
    const float* __restrict__ Wq, const float* __restrict__ Wk,
    const float* __restrict__ Wv, const float* __restrict__ bq,
    const float* __restrict__ bk, const float* __restrict__ bv,
    const float* __restrict__ Wo,
    bf16* __restrict__ WqT, bf16* __restrict__ WkT, bf16* __restrict__ WvT,
    float* __restrict__ bqp, float* __restrict__ bkp, float* __restrict__ bvp,
    bf16* __restrict__ WoT)
{
    __shared__ float T[64][68];
    const int tid = threadIdx.x, bx = blockIdx.x;
    if (bx < 384) {
        const int mat = bx / 128, rem = bx % 128;
        const int c0 = (rem >> 5) * 64, n0 = (rem & 31) * 64;
        const float* W = (mat == 0) ? Wq : (mat == 1) ? Wk : Wv;
        bf16* WT = (mat == 0) ? WqT : (mat == 1) ? WkT : WvT;
        #pragma unroll
        for (int it = 0; it < 4; ++it) {
            int pp = tid + (it << 8);
            int cl = pp >> 4, n4 = (pp & 15) * 4;
            float4 f = *(const float4*)(W + (size_t)(c0 + cl) * 2048 + n0 + n4);
            T[cl][n4] = f.x; T[cl][n4+1] = f.y; T[cl][n4+2] = f.z; T[cl][n4+3] = f.w;
        }
        __syncthreads();
        const int h = n0 >> 8, d0 = n0 & 255;
        #pragma unroll
        for (int it = 0; it < 2; ++it) {
            int pp = tid + (it << 8);
            int j = pp >> 3, g = pp & 7;
            union{unsigned short us[8]; uint4 v;} pk;
            #pragma unroll
            for (int u = 0; u < 8; ++u) pk.us[u] = f2us(T[g*8+u][j]);
            *(uint4*)(WT + (size_t)((d0 + j) * 8 + h) * 256 + c0 + g * 8) = pk.v;
        }
    } else if (bx < 387) {
        const int mat = bx - 384;
        const float* src = (mat == 0) ? bq : (mat == 1) ? bk : bv;
        float* dst = (mat == 0) ? bqp : (mat == 1) ? bkp : bvp;
        for (int n = tid; n < 2048; n += 256)
            dst[(n & 255) * 8 + (n >> 8)] = src[n];
    } else {
        const int idx = bx - 387;
        const int k0 = (idx >> 2) * 64, c0 = (idx & 3) * 64;
        #pragma unroll
        for (int it = 0; it < 4; ++it) {
            int pp = tid + (it << 8);
            int kl = pp >> 4, c4 = (pp & 15) * 4;
            float4 f = *(const float4*)(Wo + (size_t)(k0 + kl) * 256 + c0 + c4);
            T[kl][c4] = f.x; T[kl][c4+1] = f.y; T[kl][c4+2] = f.z; T[kl][c4+3] = f.w;
        }
        __syncthreads();
        #pragma unroll
        for (int it = 0; it < 2; ++it) {
            int pp = tid + (it << 8);
            int j = pp >> 3, g = pp & 7;
            union{unsigned short us[8]; uint4 v;} pk;
            #pragma unroll
            for (int u = 0; u < 8; ++u) pk.us[u] = f2us(T[g*8+u][j]);
            *(uint4*)(WoT + (size_t)(c0 + j) * 2048 + k0 + g * 8) = pk.v;
        }
    }
}

// ---------------------------------------------------------------------------
// qk: unchanged (measured 93 us structure).
// ---------------------------------------------------------------------------
__global__ __launch_bounds__(512, 2) void qk_kernel(
    const float* __restrict__ Qin, const float* __restrict__ Kin,
    const int* __restrict__ mask,
    const bf16* __restrict__ WqT, const bf16* __restrict__ WkT,
    const float* __restrict__ bqp, const float* __restrict__ bkp,
    float* __restrict__ w)
{
    __shared__ __align__(16) char smem[147456];
    char* const Xq = smem;             // [64][256] bf16 swizzled (32 KB)
    char* const Xk = smem + 32768;     // 32 KB
    char* const QT = smem + 65536;     // [256 p2][pitch 160B] (40 KB)
    char* const KT = smem + 106496;    // 40 KB
    float* const RED = (float*)smem;   // [64][68] fp32 alias over Xq

    const int tid  = threadIdx.x;
    const int wid  = tid >> 6, lane = tid & 63;
    const int quad = lane >> 4, l15 = lane & 15;
    const int tok0 = blockIdx.x * 64;

    #pragma unroll
    for (int it = 0; it < 4; ++it) {
        int pp = tid + (it << 9);
        int row = pp >> 5, g = pp & 31;
        const float* s = Qin + (size_t)(tok0 + row) * 256 + g * 8;
        *(uint4*)(Xq + row * 512 + ((g ^ (row & 7)) << 4)) =
            pack8(*(const float4*)s, *(const float4*)(s + 4));
        s = Kin + (size_t)(tok0 + row) * 256 + g * 8;
        *(uint4*)(Xk + row * 512 + ((g ^ (row & 7)) << 4)) =
            pack8(*(const float4*)s, *(const float4*)(s + 4));
    }
    __syncthreads();

    f32x4 sacc[4];
    #pragma unroll
    for (int p = 0; p < 4; ++p)
        #pragma unroll
        for (int i = 0; i < 4; ++i) sacc[p][i] = 0.f;

    for (int Cp = 0; Cp < 8; ++Cp) {
        f32x4 accq[4][2], acck[4][2];
        #pragma unroll
        for (int mt = 0; mt < 4; ++mt)
            #pragma unroll
            for (int nt = 0; nt < 2; ++nt)
                #pragma unroll
                for (int i = 0; i < 4; ++i) { accq[mt][nt][i] = 0.f; acck[mt][nt][i] = 0.f; }
        #pragma unroll
        for (int Ks = 0; Ks < 8; ++Ks) {
            bf16x8 bq[2], bk[2];
            #pragma unroll
            for (int nt = 0; nt < 2; ++nt) {
                const size_t boff =
                    (size_t)(Cp * 256 + wid * 32 + nt * 16 + l15) * 256 + Ks * 32 + quad * 8;
                bq[nt] = *(const bf16x8*)(WqT + boff);
                bk[nt] = *(const bf16x8*)(WkT + boff);
            }
            #pragma unroll
            for (int mt = 0; mt < 4; ++mt) {
                int row = mt * 16 + l15;
                int G = (Ks * 4 + quad) ^ (row & 7);
                bf16x8 aq = *(const bf16x8*)(Xq + row * 512 + (G << 4));
                bf16x8 ak = *(const bf16x8*)(Xk + row * 512 + (G << 4));
                #pragma unroll
                for (int nt = 0; nt < 2; ++nt) {
                    accq[mt][nt] = MFMA16(aq, bq[nt], accq[mt][nt]);
                    acck[mt][nt] = MFMA16(ak, bk[nt], acck[mt][nt]);
                }
            }
        }
        #pragma unroll
        for (int nt = 0; nt < 2; ++nt) {
            const int p2 = wid * 32 + nt * 16 + l15;
            const int rowoff = p2 * 160 + ((p2 >> 6) & 3) * 8;
            const float biq = bqp[Cp * 256 + p2];
            const float bik = bkp[Cp * 256 + p2];
            #pragma unroll
            for (int mt = 0; mt < 4; ++mt) {
                int t0 = mt * 16 + quad * 4;
                union{unsigned short us[4]; uint2 v;} pq, pk;
                #pragma unroll
                for (int i = 0; i < 4; ++i) {
                    pq.us[i] = f2us(accq[mt][nt][i] + biq);
                    pk.us[i] = f2us(acck[mt][nt][i] + bik);
                }
                *(uint2*)(QT + rowoff + t0 * 2) = pq.v;
                *(uint2*)(KT + rowoff + t0 * 2) = pk.v;
            }
        }
        __syncthreads();
        #pragma unroll
        for (int pp2 = 0; pp2 < 4; ++pp2) {
            int tq = 2 * (wid * 4 + pp2) + (l15 >> 3);
            union{unsigned short us[8]; bf16x8 v;} Aq, Bk;
            #pragma unroll
            for (int j = 0; j < 8; ++j) {
                int p2 = (quad * 8 + j) * 8 + (l15 & 7);
                int off = p2 * 160 + ((p2 >> 6) & 3) * 8 + tq * 2;
                Aq.us[j] = *(const unsigned short*)(QT + off);
                Bk.us[j] = *(const unsigned short*)(KT + off);
            }
            sacc[pp2] = MFMA16(Aq.v, Bk.v, sacc[pp2]);
        }
        __syncthreads();
    }

    if ((quad >> 1) == (l15 >> 3)) {
        #pragma unroll
        for (int pp2 = 0; pp2 < 4; ++pp2) {
            int tl = (wid * 4 + pp2) * 2 + (l15 >> 3);
            #pragma unroll
            for (int i = 0; i < 4; ++i)
                RED[tl * 68 + ((quad & 1) * 4 + i) * 8 + (l15 & 7)] = sacc[pp2][i];
        }
    }
    __syncthreads();
    {
        const int tl = tid >> 3, hh = tid & 7;
        const int mk = mask[tok0 + tl];
        const float* r = RED + tl * 68 + hh * 8;
        float m = r[0];
        #pragma unroll
        for (int g = 1; g < 8; ++g) m = fmaxf(m, r[g]);
        float e[8], sum = 0.f;
        #pragma unroll
        for (int g = 0; g < 8; ++g) { e[g] = __expf((r[g] - m) * 0.0625f); sum += e[g]; }
        float inv = 1.f / sum;
        float o[8];
        #pragma unroll
        for (int g = 0; g < 8; ++g) o[g] = mk ? e[g] * inv : 0.125f;
        float* wp = w + (size_t)(tok0 + tl) * 64 + hh * 8;
        *(float4*)wp = make_float4(o[0], o[1], o[2], o[3]);
        *(float4*)(wp + 4) = make_float4(o[4], o[5], o[6], o[7]);
    }
}

// ---------------------------------------------------------------------------
// av v2: fused v_attn + outproj with a skewed 1-barrier pipeline.
// VT and xS are double-buffered; each phase p runs THREE independent streams
// between a single barrier:
//   proj(C=p)      : Xv x WvT MFMA -> VT[p&1]
//   valu(C=p-1)    : VT[(p-1)&1] x w (VALU) -> xS[(p-1)&1]
//   outproj(C=p-2) : xS[p&1] x WoT MFMA -> oacc
// MFMA and VALU are separate pipes, so the weighted-sum no longer serializes
// against the two MFMA streams (round-4 counters: MfmaUtil 14% and VALUBusy
// 16.5% never overlapping). Barriers: 32 -> 18. LDS 100352 B (1 block/CU,
// same as before). No runtime-indexed register arrays (round-2 spill lesson).
// ---------------------------------------------------------------------------
__global__ __launch_bounds__(512, 2) void av_kernel(
    const float* __restrict__ Vin,
    const bf16* __restrict__ WvT, const float* __restrict__ bvp,
    const float* __restrict__ w, const bf16* __restrict__ WoT,
    const float* __restrict__ bo, float* __restrict__ Out)
{
    __shared__ __align__(16) char smem[100352];
    char* const Xv  = smem;              // [64][256] bf16 swizzled (32 KB)
    char* const VT0 = smem + 32768;      // [128 p][pitch 136B] (17408 B)
    char* const VT1 = smem + 50176;      // second buffer
    char* const xS0 = smem + 67584;      // [64 t][16 units x 16B swizzled] (16 KB)
    char* const xS1 = smem + 83968;      // second buffer

    const int tid  = threadIdx.x;
    const int wid  = tid >> 6, lane = tid & 63;
    const int quad = lane >> 4, l15 = lane & 15;
    const int tok0 = blockIdx.x * 64;
    const int t6   = tid & 63, dg = tid >> 6;

    #pragma unroll
    for (int it = 0; it < 4; ++it) {
        int pp = tid + (it << 9);
        int row = pp >> 5, g = pp & 31;
        const float* s = Vin + (size_t)(tok0 + row) * 256 + g * 8;
        *(uint4*)(Xv + row * 512 + ((g ^ (row & 7)) << 4)) =
            pack8(*(const float4*)s, *(const float4*)(s + 4));
    }
    float wv[64];
    {
        const float* wp = w + (size_t)(tok0 + t6) * 64;
        #pragma unroll
        for (int i = 0; i < 16; ++i) {
            float4 f = ((const float4*)wp)[i];
            wv[i*4] = f.x; wv[i*4+1] = f.y; wv[i*4+2] = f.z; wv[i*4+3] = f.w;
        }
    }
    __syncthreads();

    const int pll = wid * 16 + l15;

    f32x4 oacc[4][2];
    #pragma unroll
    for (int mt = 0; mt < 4; ++mt)
        #pragma unroll
        for (int nt = 0; nt < 2; ++nt)
            #pragma unroll
            for (int i = 0; i < 4; ++i) oacc[mt][nt][i] = 0.f;

    for (int p = 0; p < 18; ++p) {
        char* const VTw = (p & 1) ? VT1 : VT0;       // proj writes
        char* const VTr = (p & 1) ? VT0 : VT1;       // valu reads  ((p-1)&1)
        char* const xSw = (p & 1) ? xS0 : xS1;       // valu writes ((p-1)&1)
        char* const xSr = (p & 1) ? xS1 : xS0;       // outproj reads ((p-2)&1 == p&1)

        // --- stream 1: v-proj for chunk C = p ---
        if (p < 16) {
            const int C = p;
            f32x4 acc[4];
            #pragma unroll
            for (int mt = 0; mt < 4; ++mt)
                #pragma unroll
                for (int i = 0; i < 4; ++i) acc[mt][i] = 0.f;
            #pragma unroll
            for (int Ks = 0; Ks < 8; ++Ks) {
                bf16x8 b = *(const bf16x8*)(WvT + (size_t)(C * 128 + pll) * 256 + Ks * 32 + quad * 8);
                #pragma unroll
                for (int mt = 0; mt < 4; ++mt) {
                    int row = mt * 16 + l15;
                    int G = (Ks * 4 + quad) ^ (row & 7);
                    bf16x8 a = *(const bf16x8*)(Xv + row * 512 + (G << 4));
                    acc[mt] = MFMA16(a, b, acc[mt]);
                }
            }
            const float biv = bvp[C * 128 + pll];
            #pragma unroll
            for (int mt = 0; mt < 4; ++mt) {
                int t0 = mt * 16 + quad * 4;
                union{unsigned short us[4]; uint2 v;} pk;
                #pragma unroll
                for (int i = 0; i < 4; ++i) pk.us[i] = f2us(acc[mt][i] + biv);
                *(uint2*)(VTw + pll * 136 + t0 * 2) = pk.v;
            }
        }

        // --- stream 2: weighted sum for chunk C = p-1 (VALU pipe) ---
        if (p >= 1 && p <= 16) {
            #pragma unroll
            for (int dd = 0; dd < 2; ++dd) {
                int d = dg * 2 + dd;
                float vv[8];
                #pragma unroll
                for (int g = 0; g < 8; ++g)
                    vv[g] = us2f(*(const unsigned short*)(VTr + (d * 8 + g) * 136 + t6 * 2));
                #pragma unroll
                for (int h = 0; h < 8; ++h) {
                    float x = 0.f;
                    #pragma unroll
                    for (int g = 0; g < 8; ++g) x = fmaf(wv[h * 8 + g], vv[g], x);
                    int u = (h * 2 + (d >> 3)) ^ (t6 & 15);
                    *(unsigned short*)(xSw + t6 * 256 + u * 16 + (d & 7) * 2) = f2us(x);
                }
            }
        }

        // --- stream 3: out-proj accumulate for chunk C = p-2 ---
        if (p >= 2) {
            const int C = p - 2;
            #pragma unroll
            for (int m = 0; m < 4; ++m) {
                const int j  = 2 * m + (quad >> 1);
                const int k0 = j * 256 + C * 16 + (quad & 1) * 8;
                bf16x8 bfr[2];
                #pragma unroll
                for (int nt = 0; nt < 2; ++nt) {
                    int c = wid * 32 + nt * 16 + l15;
                    bfr[nt] = *(const bf16x8*)(WoT + (size_t)c * 2048 + k0);
                }
                #pragma unroll
                for (int mt = 0; mt < 4; ++mt) {
                    int h = mt * 2 + (l15 >> 3);
                    int t = (l15 & 7) * 8 + j;
                    int u = (h * 2 + (quad & 1)) ^ (t & 15);
                    bf16x8 afr = *(const bf16x8*)(xSr + t * 256 + u * 16);
                    #pragma unroll
                    for (int nt = 0; nt < 2; ++nt)
                        oacc[mt][nt] = MFMA16(afr, bfr[nt], oacc[mt][nt]);
                }
            }
        }

        __syncthreads();
    }

    // epilogue: bias + direct Out write in the reference's scrambled row order
    const int b = tok0 >> 11, sg0 = (tok0 & 2047) >> 3;
    #pragma unroll
    for (int nt = 0; nt < 2; ++nt) {
        int c = wid * 32 + nt * 16 + l15;
        float bias = bo[c];
        #pragma unroll
        for (int mt = 0; mt < 4; ++mt) {
            #pragma unroll
            for (int i = 0; i < 4; ++i) {
                int rr = mt * 16 + quad * 4 + i;
                int h = rr >> 3, sgl = rr & 7;
                size_t r = ((size_t)b << 11) + h * 256 + sg0 + sgl;
                Out[r * 256 + c] = oacc[mt][nt][i] + bias;
            }
        }
    }
}

// ---------------------------------------------------------------------------
extern "C" void kernel_launch(void* const* d_in, const int* in_sizes, int n_in,
                              void* d_out, int out_size, void* d_ws, size_t ws_size,
                              hipStream_t stream) {
    const float* query = (const float*)d_in[0];
    const float* key   = (const float*)d_in[1];
    const float* value = (const float*)d_in[2];
    const int*   mask  = (const int*)  d_in[3];
    const float* Wq = (const float*)d_in[4];  const float* bq = (const float*)d_in[5];
    const float* Wk = (const float*)d_in[6];  const float* bk = (const float*)d_in[7];
    const float* Wv = (const float*)d_in[8];  const float* bv = (const float*)d_in[9];
    const float* Wo = (const float*)d_in[10]; const float* bo = (const float*)d_in[11];

    // all scratch in d_ws (d_out is written directly by av_kernel):
    char* ws = (char*)d_ws;
    bf16*  WoT = (bf16*)ws;                    // [256 c][2048 k] bf16, 1 MB
    bf16*  WqT = (bf16*)(ws + 1048576);        // [2048][256] bf16, 1 MB each
    bf16*  WkT = (bf16*)(ws + 2097152);
    bf16*  WvT = (bf16*)(ws + 3145728);
    float* bqp = (float*)(ws + 4194304);
    float* bkp = (float*)(ws + 4202496);
    float* bvp = (float*)(ws + 4210688);
    float* w   = (float*)(ws + 4218880);       // [16384][64] fp32, 4 MB

    prep_kernel<<<515, 256, 0, stream>>>(
        Wq, Wk, Wv, bq, bk, bv, Wo, WqT, WkT, WvT, bqp, bkp, bvp, WoT);
    qk_kernel<<<256, 512, 0, stream>>>(
        query, key, mask, WqT, WkT, bqp, bkp, w);
    av_kernel<<<256, 512, 0, stream>>>(
        value, WvT, bvp, w, WoT, bo, (float*)d_out);
}

// Round 6
// 266.182 us; speedup vs baseline: 1.3119x; 1.0100x over previous
//
#include <hip/hip_runtime.h>
#include <hip/hip_bf16.h>

typedef __hip_bfloat16 bf16;
typedef short bf16x8 __attribute__((ext_vector_type(8)));
typedef float f32x4 __attribute__((ext_vector_type(4)));

#define MFMA16(a,b,c) __builtin_amdgcn_mfma_f32_16x16x32_bf16(a,b,c,0,0,0)

__device__ __forceinline__ unsigned short f2us(float x){
    union{__hip_bfloat16 h; unsigned short u;} c; c.h = __float2bfloat16(x); return c.u;
}
__device__ __forceinline__ float us2f(unsigned short u){
    union{unsigned short u; __hip_bfloat16 h;} c; c.u = u; return __bfloat162float(c.h);
}
__device__ __forceinline__ uint4 pack8(float4 a, float4 b){
    union{unsigned short us[8]; uint4 v;} p;
    p.us[0]=f2us(a.x); p.us[1]=f2us(a.y); p.us[2]=f2us(a.z); p.us[3]=f2us(a.w);
    p.us[4]=f2us(b.x); p.us[5]=f2us(b.y); p.us[6]=f2us(b.z); p.us[7]=f2us(b.w);
    return p.v;
}

// ---------------------------------------------------------------------------
// prep: LDS-tiled transposes (unchanged).
// ---------------------------------------------------------------------------
__global__ __launch_bounds__(256) void prep_kernel(
    const float* __restrict__ Wq, const float* __restrict__ Wk,
    const float* __restrict__ Wv, const float* __restrict__ bq,
    const float* __restrict__ bk, const float* __restrict__ bv,
    const float* __restrict__ Wo,
    bf16* __restrict__ WqT, bf16* __restrict__ WkT, bf16* __restrict__ WvT,
    float* __restrict__ bqp, float* __restrict__ bkp, float* __restrict__ bvp,
    bf16* __restrict__ WoT)
{
    __shared__ float T[64][68];
    const int tid = threadIdx.x, bx = blockIdx.x;
    if (bx < 384) {
        const int mat = bx / 128, rem = bx % 128;
        const int c0 = (rem >> 5) * 64, n0 = (rem & 31) * 64;
        const float* W = (mat == 0) ? Wq : (mat == 1) ? Wk : Wv;
        bf16* WT = (mat == 0) ? WqT : (mat == 1) ? WkT : WvT;
        #pragma unroll
        for (int it = 0; it < 4; ++it) {
            int pp = tid + (it << 8);
            int cl = pp >> 4, n4 = (pp & 15) * 4;
            float4 f = *(const float4*)(W + (size_t)(c0 + cl) * 2048 + n0 + n4);
            T[cl][n4] = f.x; T[cl][n4+1] = f.y; T[cl][n4+2] = f.z; T[cl][n4+3] = f.w;
        }
        __syncthreads();
        const int h = n0 >> 8, d0 = n0 & 255;
        #pragma unroll
        for (int it = 0; it < 2; ++it) {
            int pp = tid + (it << 8);
            int j = pp >> 3, g = pp & 7;
            union{unsigned short us[8]; uint4 v;} pk;
            #pragma unroll
            for (int u = 0; u < 8; ++u) pk.us[u] = f2us(T[g*8+u][j]);
            *(uint4*)(WT + (size_t)((d0 + j) * 8 + h) * 256 + c0 + g * 8) = pk.v;
        }
    } else if (bx < 387) {
        const int mat = bx - 384;
        const float* src = (mat == 0) ? bq : (mat == 1) ? bk : bv;
        float* dst = (mat == 0) ? bqp : (mat == 1) ? bkp : bvp;
        for (int n = tid; n < 2048; n += 256)
            dst[(n & 255) * 8 + (n >> 8)] = src[n];
    } else {
        const int idx = bx - 387;
        const int k0 = (idx >> 2) * 64, c0 = (idx & 3) * 64;
        #pragma unroll
        for (int it = 0; it < 4; ++it) {
            int pp = tid + (it << 8);
            int kl = pp >> 4, c4 = (pp & 15) * 4;
            float4 f = *(const float4*)(Wo + (size_t)(k0 + kl) * 256 + c0 + c4);
            T[kl][c4] = f.x; T[kl][c4+1] = f.y; T[kl][c4+2] = f.z; T[kl][c4+3] = f.w;
        }
        __syncthreads();
        #pragma unroll
        for (int it = 0; it < 2; ++it) {
            int pp = tid + (it << 8);
            int j = pp >> 3, g = pp & 7;
            union{unsigned short us[8]; uint4 v;} pk;
            #pragma unroll
            for (int u = 0; u < 8; ++u) pk.us[u] = f2us(T[g*8+u][j]);
            *(uint4*)(WoT + (size_t)(c0 + j) * 2048 + k0 + g * 8) = pk.v;
        }
    }
}

// ---------------------------------------------------------------------------
// qk v5: 64 tokens/block, 1024 threads (16 waves), grid 256.
// Same per-CU work, weight traffic, and LDS as the 93.7us 512-thread version,
// but spread over 16 waves -> 4 waves/SIMD (vs 2), doubling the number of
// independent instruction streams available to hide L2 B-frag latency and
// barrier drains (rounds 0-4 showed qk is latency-bound: all pipes <20%).
// Each wave owns a 16-col slice (pll = wid*16+l15, wid in [0,16)); acc
// arrays halve -> VGPR well under the 128 budget at 4 waves/SIMD.
// ---------------------------------------------------------------------------
__global__ __launch_bounds__(1024, 4) void qk_kernel(
    const float* __restrict__ Qin, const float* __restrict__ Kin,
    const int* __restrict__ mask,
    const bf16* __restrict__ WqT, const bf16* __restrict__ WkT,
    const float* __restrict__ bqp, const float* __restrict__ bkp,
    float* __restrict__ w)
{
    __shared__ __align__(16) char smem[147456];
    char* const Xq = smem;             // [64][256] bf16 swizzled (32 KB)
    char* const Xk = smem + 32768;     // 32 KB
    char* const QT = smem + 65536;     // [256 p2][pitch 160B] (40 KB)
    char* const KT = smem + 106496;    // 40 KB
    float* const RED = (float*)smem;   // [64][68] fp32 alias over Xq

    const int tid  = threadIdx.x;
    const int wid  = tid >> 6, lane = tid & 63;
    const int quad = lane >> 4, l15 = lane & 15;
    const int tok0 = blockIdx.x * 64;

    // stage Xq, Xk once (fp32 -> bf16, XOR-swizzled 16B groups)
    #pragma unroll
    for (int it = 0; it < 2; ++it) {
        int pp = tid + (it << 10);
        int row = pp >> 5, g = pp & 31;
        const float* s = Qin + (size_t)(tok0 + row) * 256 + g * 8;
        *(uint4*)(Xq + row * 512 + ((g ^ (row & 7)) << 4)) =
            pack8(*(const float4*)s, *(const float4*)(s + 4));
        s = Kin + (size_t)(tok0 + row) * 256 + g * 8;
        *(uint4*)(Xk + row * 512 + ((g ^ (row & 7)) << 4)) =
            pack8(*(const float4*)s, *(const float4*)(s + 4));
    }
    __syncthreads();

    const int pll = wid * 16 + l15;    // block-local column 0..255

    f32x4 sacc[2];
    #pragma unroll
    for (int p = 0; p < 2; ++p)
        #pragma unroll
        for (int i = 0; i < 4; ++i) sacc[p][i] = 0.f;

    for (int Cp = 0; Cp < 8; ++Cp) {
        // --- projection: wave computes 64 tokens x 16 cols for Q and K ---
        f32x4 accq[4], acck[4];
        #pragma unroll
        for (int mt = 0; mt < 4; ++mt)
            #pragma unroll
            for (int i = 0; i < 4; ++i) { accq[mt][i] = 0.f; acck[mt][i] = 0.f; }
        #pragma unroll
        for (int Ks = 0; Ks < 8; ++Ks) {
            const size_t boff =
                (size_t)(Cp * 256 + pll) * 256 + Ks * 32 + quad * 8;
            bf16x8 bq = *(const bf16x8*)(WqT + boff);
            bf16x8 bk = *(const bf16x8*)(WkT + boff);
            #pragma unroll
            for (int mt = 0; mt < 4; ++mt) {
                int row = mt * 16 + l15;
                int G = (Ks * 4 + quad) ^ (row & 7);
                bf16x8 aq = *(const bf16x8*)(Xq + row * 512 + (G << 4));
                bf16x8 ak = *(const bf16x8*)(Xk + row * 512 + (G << 4));
                accq[mt] = MFMA16(aq, bq, accq[mt]);
                acck[mt] = MFMA16(ak, bk, acck[mt]);
            }
        }
        {
            const int p2 = pll;
            const int rowoff = p2 * 160 + ((p2 >> 6) & 3) * 8;
            const float biq = bqp[Cp * 256 + p2];
            const float bik = bkp[Cp * 256 + p2];
            #pragma unroll
            for (int mt = 0; mt < 4; ++mt) {
                int t0 = mt * 16 + quad * 4;
                union{unsigned short us[4]; uint2 v;} pq, pk;
                #pragma unroll
                for (int i = 0; i < 4; ++i) {
                    pq.us[i] = f2us(accq[mt][i] + biq);
                    pk.us[i] = f2us(acck[mt][i] + bik);
                }
                *(uint2*)(QT + rowoff + t0 * 2) = pq.v;
                *(uint2*)(KT + rowoff + t0 * 2) = pk.v;
            }
        }
        __syncthreads();
        // block-diagonal score MFMA: 2 token-pairs per wave (16 waves)
        #pragma unroll
        for (int pp2 = 0; pp2 < 2; ++pp2) {
            int tq = 2 * (wid * 2 + pp2) + (l15 >> 3);
            union{unsigned short us[8]; bf16x8 v;} Aq, Bk;
            #pragma unroll
            for (int j = 0; j < 8; ++j) {
                int p2 = (quad * 8 + j) * 8 + (l15 & 7);
                int off = p2 * 160 + ((p2 >> 6) & 3) * 8 + tq * 2;
                Aq.us[j] = *(const unsigned short*)(QT + off);
                Bk.us[j] = *(const unsigned short*)(KT + off);
            }
            sacc[pp2] = MFMA16(Aq.v, Bk.v, sacc[pp2]);
        }
        __syncthreads();
    }

    // diagonal extraction -> RED[t][h*8+g]
    if ((quad >> 1) == (l15 >> 3)) {
        #pragma unroll
        for (int pp2 = 0; pp2 < 2; ++pp2) {
            int tl = (wid * 2 + pp2) * 2 + (l15 >> 3);
            #pragma unroll
            for (int i = 0; i < 4; ++i)
                RED[tl * 68 + ((quad & 1) * 4 + i) * 8 + (l15 & 7)] = sacc[pp2][i];
        }
    }
    __syncthreads();
    // softmax: thread (tl, h) -- 64 tokens x 8 heads = first 512 threads
    if (tid < 512) {
        const int tl = tid >> 3, hh = tid & 7;
        const int mk = mask[tok0 + tl];
        const float* r = RED + tl * 68 + hh * 8;
        float m = r[0];
        #pragma unroll
        for (int g = 1; g < 8; ++g) m = fmaxf(m, r[g]);
        float e[8], sum = 0.f;
        #pragma unroll
        for (int g = 0; g < 8; ++g) { e[g] = __expf((r[g] - m) * 0.0625f); sum += e[g]; }
        float inv = 1.f / sum;
        float o[8];
        #pragma unroll
        for (int g = 0; g < 8; ++g) o[g] = mk ? e[g] * inv : 0.125f;
        float* wp = w + (size_t)(tok0 + tl) * 64 + hh * 8;
        *(float4*)wp = make_float4(o[0], o[1], o[2], o[3]);
        *(float4*)(wp + 4) = make_float4(o[4], o[5], o[6], o[7]);
    }
}

// ---------------------------------------------------------------------------
// av v2: unchanged from round 4 (fused v_attn+outproj, skewed pipeline).
// ---------------------------------------------------------------------------
__global__ __launch_bounds__(512, 2) void av_kernel(
    const float* __restrict__ Vin,
    const bf16* __restrict__ WvT, const float* __restrict__ bvp,
    const float* __restrict__ w, const bf16* __restrict__ WoT,
    const float* __restrict__ bo, float* __restrict__ Out)
{
    __shared__ __align__(16) char smem[100352];
    char* const Xv  = smem;              // [64][256] bf16 swizzled (32 KB)
    char* const VT0 = smem + 32768;      // [128 p][pitch 136B] (17408 B)
    char* const VT1 = smem + 50176;      // second buffer
    char* const xS0 = smem + 67584;      // [64 t][16 units x 16B swizzled] (16 KB)
    char* const xS1 = smem + 83968;      // second buffer

    const int tid  = threadIdx.x;
    const int wid  = tid >> 6, lane = tid & 63;
    const int quad = lane >> 4, l15 = lane & 15;
    const int tok0 = blockIdx.x * 64;
    const int t6   = tid & 63, dg = tid >> 6;

    #pragma unroll
    for (int it = 0; it < 4; ++it) {
        int pp = tid + (it << 9);
        int row = pp >> 5, g = pp & 31;
        const float* s = Vin + (size_t)(tok0 + row) * 256 + g * 8;
        *(uint4*)(Xv + row * 512 + ((g ^ (row & 7)) << 4)) =
            pack8(*(const float4*)s, *(const float4*)(s + 4));
    }
    float wv[64];
    {
        const float* wp = w + (size_t)(tok0 + t6) * 64;
        #pragma unroll
        for (int i = 0; i < 16; ++i) {
            float4 f = ((const float4*)wp)[i];
            wv[i*4] = f.x; wv[i*4+1] = f.y; wv[i*4+2] = f.z; wv[i*4+3] = f.w;
        }
    }
    __syncthreads();

    const int pll = wid * 16 + l15;

    f32x4 oacc[4][2];
    #pragma unroll
    for (int mt = 0; mt < 4; ++mt)
        #pragma unroll
        for (int nt = 0; nt < 2; ++nt)
            #pragma unroll
            for (int i = 0; i < 4; ++i) oacc[mt][nt][i] = 0.f;

    for (int p = 0; p < 18; ++p) {
        char* const VTw = (p & 1) ? VT1 : VT0;       // proj writes
        char* const VTr = (p & 1) ? VT0 : VT1;       // valu reads  ((p-1)&1)
        char* const xSw = (p & 1) ? xS0 : xS1;       // valu writes ((p-1)&1)
        char* const xSr = (p & 1) ? xS1 : xS0;       // outproj reads ((p-2)&1 == p&1)

        // --- stream 1: v-proj for chunk C = p ---
        if (p < 16) {
            const int C = p;
            f32x4 acc[4];
            #pragma unroll
            for (int mt = 0; mt < 4; ++mt)
                #pragma unroll
                for (int i = 0; i < 4; ++i) acc[mt][i] = 0.f;
            #pragma unroll
            for (int Ks = 0; Ks < 8; ++Ks) {
                bf16x8 b = *(const bf16x8*)(WvT + (size_t)(C * 128 + pll) * 256 + Ks * 32 + quad * 8);
                #pragma unroll
                for (int mt = 0; mt < 4; ++mt) {
                    int row = mt * 16 + l15;
                    int G = (Ks * 4 + quad) ^ (row & 7);
                    bf16x8 a = *(const bf16x8*)(Xv + row * 512 + (G << 4));
                    acc[mt] = MFMA16(a, b, acc[mt]);
                }
            }
            const float biv = bvp[C * 128 + pll];
            #pragma unroll
            for (int mt = 0; mt < 4; ++mt) {
                int t0 = mt * 16 + quad * 4;
                union{unsigned short us[4]; uint2 v;} pk;
                #pragma unroll
                for (int i = 0; i < 4; ++i) pk.us[i] = f2us(acc[mt][i] + biv);
                *(uint2*)(VTw + pll * 136 + t0 * 2) = pk.v;
            }
        }

        // --- stream 2: weighted sum for chunk C = p-1 (VALU pipe) ---
        if (p >= 1 && p <= 16) {
            #pragma unroll
            for (int dd = 0; dd < 2; ++dd) {
                int d = dg * 2 + dd;
                float vv[8];
                #pragma unroll
                for (int g = 0; g < 8; ++g)
                    vv[g] = us2f(*(const unsigned short*)(VTr + (d * 8 + g) * 136 + t6 * 2));
                #pragma unroll
                for (int h = 0; h < 8; ++h) {
                    float x = 0.f;
                    #pragma unroll
                    for (int g = 0; g < 8; ++g) x = fmaf(wv[h * 8 + g], vv[g], x);
                    int u = (h * 2 + (d >> 3)) ^ (t6 & 15);
                    *(unsigned short*)(xSw + t6 * 256 + u * 16 + (d & 7) * 2) = f2us(x);
                }
            }
        }

        // --- stream 3: out-proj accumulate for chunk C = p-2 ---
        if (p >= 2) {
            const int C = p - 2;
            #pragma unroll
            for (int m = 0; m < 4; ++m) {
                const int j  = 2 * m + (quad >> 1);
                const int k0 = j * 256 + C * 16 + (quad & 1) * 8;
                bf16x8 bfr[2];
                #pragma unroll
                for (int nt = 0; nt < 2; ++nt) {
                    int c = wid * 32 + nt * 16 + l15;
                    bfr[nt] = *(const bf16x8*)(WoT + (size_t)c * 2048 + k0);
                }
                #pragma unroll
                for (int mt = 0; mt < 4; ++mt) {
                    int h = mt * 2 + (l15 >> 3);
                    int t = (l15 & 7) * 8 + j;
                    int u = (h * 2 + (quad & 1)) ^ (t & 15);
                    bf16x8 afr = *(const bf16x8*)(xSr + t * 256 + u * 16);
                    #pragma unroll
                    for (int nt = 0; nt < 2; ++nt)
                        oacc[mt][nt] = MFMA16(afr, bfr[nt], oacc[mt][nt]);
                }
            }
        }

        __syncthreads();
    }

    // epilogue: bias + direct Out write in the reference's scrambled row order
    const int b = tok0 >> 11, sg0 = (tok0 & 2047) >> 3;
    #pragma unroll
    for (int nt = 0; nt < 2; ++nt) {
        int c = wid * 32 + nt * 16 + l15;
        float bias = bo[c];
        #pragma unroll
        for (int mt = 0; mt < 4; ++mt) {
            #pragma unroll
            for (int i = 0; i < 4; ++i) {
                int rr = mt * 16 + quad * 4 + i;
                int h = rr >> 3, sgl = rr & 7;
                size_t r = ((size_t)b << 11) + h * 256 + sg0 + sgl;
                Out[r * 256 + c] = oacc[mt][nt][i] + bias;
            }
        }
    }
}

// ---------------------------------------------------------------------------
extern "C" void kernel_launch(void* const* d_in, const int* in_sizes, int n_in,
                              void* d_out, int out_size, void* d_ws, size_t ws_size,
                              hipStream_t stream) {
    const float* query = (const float*)d_in[0];
    const float* key   = (const float*)d_in[1];
    const float* value = (const float*)d_in[2];
    const int*   mask  = (const int*)  d_in[3];
    const float* Wq = (const float*)d_in[4];  const float* bq = (const float*)d_in[5];
    const float* Wk = (const float*)d_in[6];  const float* bk = (const float*)d_in[7];
    const float* Wv = (const float*)d_in[8];  const float* bv = (const float*)d_in[9];
    const float* Wo = (const float*)d_in[10]; const float* bo = (const float*)d_in[11];

    // all scratch in d_ws (d_out is written directly by av_kernel):
    char* ws = (char*)d_ws;
    bf16*  WoT = (bf16*)ws;                    // [256 c][2048 k] bf16, 1 MB
    bf16*  WqT = (bf16*)(ws + 1048576);        // [2048][256] bf16, 1 MB each
    bf16*  WkT = (bf16*)(ws + 2097152);
    bf16*  WvT = (bf16*)(ws + 3145728);
    float* bqp = (float*)(ws + 4194304);
    float* bkp = (float*)(ws + 4202496);
    float* bvp = (float*)(ws + 4210688);
    float* w   = (float*)(ws + 4218880);       // [16384][64] fp32, 4 MB

    prep_kernel<<<515, 256, 0, stream>>>(
        Wq, Wk, Wv, bq, bk, bv, Wo, WqT, WkT, WvT, bqp, bkp, bvp, WoT);
    qk_kernel<<<256, 1024, 0, stream>>>(
        query, key, mask, WqT, WkT, bqp, bkp, w);
    av_kernel<<<256, 512, 0, stream>>>(
        value, WvT, bvp, w, WoT, bo, (float*)d_out);
}

// Round 7
// 262.738 us; speedup vs baseline: 1.3291x; 1.0131x over previous
//
#include <hip/hip_runtime.h>
#include <hip/hip_bf16.h>

typedef __hip_bfloat16 bf16;
typedef short bf16x8 __attribute__((ext_vector_type(8)));
typedef float f32x4 __attribute__((ext_vector_type(4)));

#define MFMA16(a,b,c) __builtin_amdgcn_mfma_f32_16x16x32_bf16(a,b,c,0,0,0)

__device__ __forceinline__ unsigned short f2us(float x){
    union{__hip_bfloat16 h; unsigned short u;} c; c.h = __float2bfloat16(x); return c.u;
}
__device__ __forceinline__ float us2f(unsigned short u){
    union{unsigned short u; __hip_bfloat16 h;} c; c.u = u; return __bfloat162float(c.h);
}
__device__ __forceinline__ uint4 pack8(float4 a, float4 b){
    union{unsigned short us[8]; uint4 v;} p;
    p.us[0]=f2us(a.x); p.us[1]=f2us(a.y); p.us[2]=f2us(a.z); p.us[3]=f2us(a.w);
    p.us[4]=f2us(b.x); p.us[5]=f2us(b.y); p.us[6]=f2us(b.z); p.us[7]=f2us(b.w);
    return p.v;
}

// ---------------------------------------------------------------------------
// prep: LDS-tiled transposes (unchanged).
// ---------------------------------------------------------------------------
__global__ __launch_bounds__(256) void prep_kernel(
    const float* __restrict__ Wq, const float* __restrict__ Wk,
    const float* __restrict__ Wv, const float* __restrict__ bq,
    const float* __restrict__ bk, const float* __restrict__ bv,
    const float* __restrict__ Wo,
    bf16* __restrict__ WqT, bf16* __restrict__ WkT, bf16* __restrict__ WvT,
    float* __restrict__ bqp, float* __restrict__ bkp, float* __restrict__ bvp,
    bf16* __restrict__ WoT)
{
    __shared__ float T[64][68];
    const int tid = threadIdx.x, bx = blockIdx.x;
    if (bx < 384) {
        const int mat = bx / 128, rem = bx % 128;
        const int c0 = (rem >> 5) * 64, n0 = (rem & 31) * 64;
        const float* W = (mat == 0) ? Wq : (mat == 1) ? Wk : Wv;
        bf16* WT = (mat == 0) ? WqT : (mat == 1) ? WkT : WvT;
        #pragma unroll
        for (int it = 0; it < 4; ++it) {
            int pp = tid + (it << 8);
            int cl = pp >> 4, n4 = (pp & 15) * 4;
            float4 f = *(const float4*)(W + (size_t)(c0 + cl) * 2048 + n0 + n4);
            T[cl][n4] = f.x; T[cl][n4+1] = f.y; T[cl][n4+2] = f.z; T[cl][n4+3] = f.w;
        }
        __syncthreads();
        const int h = n0 >> 8, d0 = n0 & 255;
        #pragma unroll
        for (int it = 0; it < 2; ++it) {
            int pp = tid + (it << 8);
            int j = pp >> 3, g = pp & 7;
            union{unsigned short us[8]; uint4 v;} pk;
            #pragma unroll
            for (int u = 0; u < 8; ++u) pk.us[u] = f2us(T[g*8+u][j]);
            *(uint4*)(WT + (size_t)((d0 + j) * 8 + h) * 256 + c0 + g * 8) = pk.v;
        }
    } else if (bx < 387) {
        const int mat = bx - 384;
        const float* src = (mat == 0) ? bq : (mat == 1) ? bk : bv;
        float* dst = (mat == 0) ? bqp : (mat == 1) ? bkp : bvp;
        for (int n = tid; n < 2048; n += 256)
            dst[(n & 255) * 8 + (n >> 8)] = src[n];
    } else {
        const int idx = bx - 387;
        const int k0 = (idx >> 2) * 64, c0 = (idx & 3) * 64;
        #pragma unroll
        for (int it = 0; it < 4; ++it) {
            int pp = tid + (it << 8);
            int kl = pp >> 4, c4 = (pp & 15) * 4;
            float4 f = *(const float4*)(Wo + (size_t)(k0 + kl) * 256 + c0 + c4);
            T[kl][c4] = f.x; T[kl][c4+1] = f.y; T[kl][c4+2] = f.z; T[kl][c4+3] = f.w;
        }
        __syncthreads();
        #pragma unroll
        for (int it = 0; it < 2; ++it) {
            int pp = tid + (it << 8);
            int j = pp >> 3, g = pp & 7;
            union{unsigned short us[8]; uint4 v;} pk;
            #pragma unroll
            for (int u = 0; u < 8; ++u) pk.us[u] = f2us(T[g*8+u][j]);
            *(uint4*)(WoT + (size_t)(c0 + j) * 2048 + k0 + g * 8) = pk.v;
        }
    }
}

// ---------------------------------------------------------------------------
// qkav: fused qk + av. One 512-thread block handles 64 tokens end-to-end.
// Phase 1 = round-0 qk body (93.7us measured). Softmax writes w to LDS
// (pitch-68 fp32, conflict-free float4 R/W) instead of HBM. Phase 2 =
// round-4 av body (95us measured) in re-aliased LDS.
// LDS lifetime map (147456 B total):
//   phase1: Xq[0,32K) Xk[32K,64K) QT[64K,104K) KT[104K,144K)
//   RED = [64][68] f32 alias @0 (after Xq dead)
//   W   = [64][68] f32 @106496 (over dead KT; read until wv load)
//   phase2: Xv[0,32K) VT0@32768 VT1@50176 xS0@67584 xS1@83968 (ends 100352,
//           below W @106496 -> W safe until consumed)
// Eliminates: one kernel launch + device-wide drain, 8 MB w round-trip,
// one extra staging pass.
// ---------------------------------------------------------------------------
__global__ __launch_bounds__(512, 2) void qkav_kernel(
    const float* __restrict__ Qin, const float* __restrict__ Kin,
    const float* __restrict__ Vin, const int* __restrict__ mask,
    const bf16* __restrict__ WqT, const bf16* __restrict__ WkT,
    const bf16* __restrict__ WvT,
    const float* __restrict__ bqp, const float* __restrict__ bkp,
    const float* __restrict__ bvp,
    const bf16* __restrict__ WoT, const float* __restrict__ bo,
    float* __restrict__ Out)
{
    __shared__ __align__(16) char smem[147456];
    // phase 1 aliases
    char* const Xq = smem;
    char* const Xk = smem + 32768;
    char* const QT = smem + 65536;
    char* const KT = smem + 106496;
    float* const RED  = (float*)smem;            // [64][68] over Xq
    float* const WLDS = (float*)(smem + 106496); // [64][68] over KT (later)
    // phase 2 aliases
    char* const Xv  = smem;
    char* const VT0 = smem + 32768;
    char* const VT1 = smem + 50176;
    char* const xS0 = smem + 67584;
    char* const xS1 = smem + 83968;

    const int tid  = threadIdx.x;
    const int wid  = tid >> 6, lane = tid & 63;
    const int quad = lane >> 4, l15 = lane & 15;
    const int tok0 = blockIdx.x * 64;
    const int t6   = tid & 63, dg = tid >> 6;

    // ---------------- phase 1: Q/K projection + scores -----------------
    #pragma unroll
    for (int it = 0; it < 4; ++it) {
        int pp = tid + (it << 9);
        int row = pp >> 5, g = pp & 31;
        const float* s = Qin + (size_t)(tok0 + row) * 256 + g * 8;
        *(uint4*)(Xq + row * 512 + ((g ^ (row & 7)) << 4)) =
            pack8(*(const float4*)s, *(const float4*)(s + 4));
        s = Kin + (size_t)(tok0 + row) * 256 + g * 8;
        *(uint4*)(Xk + row * 512 + ((g ^ (row & 7)) << 4)) =
            pack8(*(const float4*)s, *(const float4*)(s + 4));
    }
    __syncthreads();

    f32x4 sacc[4];
    #pragma unroll
    for (int p = 0; p < 4; ++p)
        #pragma unroll
        for (int i = 0; i < 4; ++i) sacc[p][i] = 0.f;

    for (int Cp = 0; Cp < 8; ++Cp) {
        f32x4 accq[4][2], acck[4][2];
        #pragma unroll
        for (int mt = 0; mt < 4; ++mt)
            #pragma unroll
            for (int nt = 0; nt < 2; ++nt)
                #pragma unroll
                for (int i = 0; i < 4; ++i) { accq[mt][nt][i] = 0.f; acck[mt][nt][i] = 0.f; }
        #pragma unroll
        for (int Ks = 0; Ks < 8; ++Ks) {
            bf16x8 bq[2], bk[2];
            #pragma unroll
            for (int nt = 0; nt < 2; ++nt) {
                const size_t boff =
                    (size_t)(Cp * 256 + wid * 32 + nt * 16 + l15) * 256 + Ks * 32 + quad * 8;
                bq[nt] = *(const bf16x8*)(WqT + boff);
                bk[nt] = *(const bf16x8*)(WkT + boff);
            }
            #pragma unroll
            for (int mt = 0; mt < 4; ++mt) {
                int row = mt * 16 + l15;
                int G = (Ks * 4 + quad) ^ (row & 7);
                bf16x8 aq = *(const bf16x8*)(Xq + row * 512 + (G << 4));
                bf16x8 ak = *(const bf16x8*)(Xk + row * 512 + (G << 4));
                #pragma unroll
                for (int nt = 0; nt < 2; ++nt) {
                    accq[mt][nt] = MFMA16(aq, bq[nt], accq[mt][nt]);
                    acck[mt][nt] = MFMA16(ak, bk[nt], acck[mt][nt]);
                }
            }
        }
        #pragma unroll
        for (int nt = 0; nt < 2; ++nt) {
            const int p2 = wid * 32 + nt * 16 + l15;
            const int rowoff = p2 * 160 + ((p2 >> 6) & 3) * 8;
            const float biq = bqp[Cp * 256 + p2];
            const float bik = bkp[Cp * 256 + p2];
            #pragma unroll
            for (int mt = 0; mt < 4; ++mt) {
                int t0 = mt * 16 + quad * 4;
                union{unsigned short us[4]; uint2 v;} pq, pk;
                #pragma unroll
                for (int i = 0; i < 4; ++i) {
                    pq.us[i] = f2us(accq[mt][nt][i] + biq);
                    pk.us[i] = f2us(acck[mt][nt][i] + bik);
                }
                *(uint2*)(QT + rowoff + t0 * 2) = pq.v;
                *(uint2*)(KT + rowoff + t0 * 2) = pk.v;
            }
        }
        __syncthreads();
        #pragma unroll
        for (int pp2 = 0; pp2 < 4; ++pp2) {
            int tq = 2 * (wid * 4 + pp2) + (l15 >> 3);
            union{unsigned short us[8]; bf16x8 v;} Aq, Bk;
            #pragma unroll
            for (int j = 0; j < 8; ++j) {
                int p2 = (quad * 8 + j) * 8 + (l15 & 7);
                int off = p2 * 160 + ((p2 >> 6) & 3) * 8 + tq * 2;
                Aq.us[j] = *(const unsigned short*)(QT + off);
                Bk.us[j] = *(const unsigned short*)(KT + off);
            }
            sacc[pp2] = MFMA16(Aq.v, Bk.v, sacc[pp2]);
        }
        __syncthreads();
    }

    // diagonal extraction -> RED[t][h*8+g]  (Xq dead, KT dead after this bar)
    if ((quad >> 1) == (l15 >> 3)) {
        #pragma unroll
        for (int pp2 = 0; pp2 < 4; ++pp2) {
            int tl = (wid * 4 + pp2) * 2 + (l15 >> 3);
            #pragma unroll
            for (int i = 0; i < 4; ++i)
                RED[tl * 68 + ((quad & 1) * 4 + i) * 8 + (l15 & 7)] = sacc[pp2][i];
        }
    }
    __syncthreads();
    // softmax: thread (tl, h) -> WLDS (pitch 68 fp32)
    {
        const int tl = tid >> 3, hh = tid & 7;
        const int mk = mask[tok0 + tl];
        const float* r = RED + tl * 68 + hh * 8;
        float m = r[0];
        #pragma unroll
        for (int g = 1; g < 8; ++g) m = fmaxf(m, r[g]);
        float e[8], sum = 0.f;
        #pragma unroll
        for (int g = 0; g < 8; ++g) { e[g] = __expf((r[g] - m) * 0.0625f); sum += e[g]; }
        float inv = 1.f / sum;
        float o[8];
        #pragma unroll
        for (int g = 0; g < 8; ++g) o[g] = mk ? e[g] * inv : 0.125f;
        float* wp = WLDS + tl * 68 + hh * 8;
        *(float4*)wp = make_float4(o[0], o[1], o[2], o[3]);
        *(float4*)(wp + 4) = make_float4(o[4], o[5], o[6], o[7]);
    }
    __syncthreads();   // WLDS visible; RED fully read before Xv overwrite

    // ---------------- phase 2: V projection + wsum + out-proj ----------
    // wv from LDS (stride 68 f32 -> lane bank = t6*17 % 32, conflict-free)
    float wv[64];
    {
        const float* wl = WLDS + t6 * 68;
        #pragma unroll
        for (int i = 0; i < 16; ++i) {
            float4 f = *(const float4*)(wl + i * 4);
            wv[i*4] = f.x; wv[i*4+1] = f.y; wv[i*4+2] = f.z; wv[i*4+3] = f.w;
        }
    }
    #pragma unroll
    for (int it = 0; it < 4; ++it) {
        int pp = tid + (it << 9);
        int row = pp >> 5, g = pp & 31;
        const float* s = Vin + (size_t)(tok0 + row) * 256 + g * 8;
        *(uint4*)(Xv + row * 512 + ((g ^ (row & 7)) << 4)) =
            pack8(*(const float4*)s, *(const float4*)(s + 4));
    }
    __syncthreads();

    const int pll = wid * 16 + l15;

    f32x4 oacc[4][2];
    #pragma unroll
    for (int mt = 0; mt < 4; ++mt)
        #pragma unroll
        for (int nt = 0; nt < 2; ++nt)
            #pragma unroll
            for (int i = 0; i < 4; ++i) oacc[mt][nt][i] = 0.f;

    for (int p = 0; p < 18; ++p) {
        char* const VTw = (p & 1) ? VT1 : VT0;
        char* const VTr = (p & 1) ? VT0 : VT1;
        char* const xSw = (p & 1) ? xS0 : xS1;
        char* const xSr = (p & 1) ? xS1 : xS0;

        // --- stream 1: v-proj for chunk C = p ---
        if (p < 16) {
            const int C = p;
            f32x4 acc[4];
            #pragma unroll
            for (int mt = 0; mt < 4; ++mt)
                #pragma unroll
                for (int i = 0; i < 4; ++i) acc[mt][i] = 0.f;
            #pragma unroll
            for (int Ks = 0; Ks < 8; ++Ks) {
                bf16x8 b = *(const bf16x8*)(WvT + (size_t)(C * 128 + pll) * 256 + Ks * 32 + quad * 8);
                #pragma unroll
                for (int mt = 0; mt < 4; ++mt) {
                    int row = mt * 16 + l15;
                    int G = (Ks * 4 + quad) ^ (row & 7);
                    bf16x8 a = *(const bf16x8*)(Xv + row * 512 + (G << 4));
                    acc[mt] = MFMA16(a, b, acc[mt]);
                }
            }
            const float biv = bvp[C * 128 + pll];
            #pragma unroll
            for (int mt = 0; mt < 4; ++mt) {
                int t0 = mt * 16 + quad * 4;
                union{unsigned short us[4]; uint2 v;} pk;
                #pragma unroll
                for (int i = 0; i < 4; ++i) pk.us[i] = f2us(acc[mt][i] + biv);
                *(uint2*)(VTw + pll * 136 + t0 * 2) = pk.v;
            }
        }

        // --- stream 2: weighted sum for chunk C = p-1 (VALU pipe) ---
        if (p >= 1 && p <= 16) {
            #pragma unroll
            for (int dd = 0; dd < 2; ++dd) {
                int d = dg * 2 + dd;
                float vv[8];
                #pragma unroll
                for (int g = 0; g < 8; ++g)
                    vv[g] = us2f(*(const unsigned short*)(VTr + (d * 8 + g) * 136 + t6 * 2));
                #pragma unroll
                for (int h = 0; h < 8; ++h) {
                    float x = 0.f;
                    #pragma unroll
                    for (int g = 0; g < 8; ++g) x = fmaf(wv[h * 8 + g], vv[g], x);
                    int u = (h * 2 + (d >> 3)) ^ (t6 & 15);
                    *(unsigned short*)(xSw + t6 * 256 + u * 16 + (d & 7) * 2) = f2us(x);
                }
            }
        }

        // --- stream 3: out-proj accumulate for chunk C = p-2 ---
        if (p >= 2) {
            const int C = p - 2;
            #pragma unroll
            for (int m = 0; m < 4; ++m) {
                const int j  = 2 * m + (quad >> 1);
                const int k0 = j * 256 + C * 16 + (quad & 1) * 8;
                bf16x8 bfr[2];
                #pragma unroll
                for (int nt = 0; nt < 2; ++nt) {
                    int c = wid * 32 + nt * 16 + l15;
                    bfr[nt] = *(const bf16x8*)(WoT + (size_t)c * 2048 + k0);
                }
                #pragma unroll
                for (int mt = 0; mt < 4; ++mt) {
                    int h = mt * 2 + (l15 >> 3);
                    int t = (l15 & 7) * 8 + j;
                    int u = (h * 2 + (quad & 1)) ^ (t & 15);
                    bf16x8 afr = *(const bf16x8*)(xSr + t * 256 + u * 16);
                    #pragma unroll
                    for (int nt = 0; nt < 2; ++nt)
                        oacc[mt][nt] = MFMA16(afr, bfr[nt], oacc[mt][nt]);
                }
            }
        }

        __syncthreads();
    }

    // epilogue: bias + direct Out write (reference's transpose-reshape rows)
    const int b = tok0 >> 11, sg0 = (tok0 & 2047) >> 3;
    #pragma unroll
    for (int nt = 0; nt < 2; ++nt) {
        int c = wid * 32 + nt * 16 + l15;
        float bias = bo[c];
        #pragma unroll
        for (int mt = 0; mt < 4; ++mt) {
            #pragma unroll
            for (int i = 0; i < 4; ++i) {
                int rr = mt * 16 + quad * 4 + i;
                int h = rr >> 3, sgl = rr & 7;
                size_t r = ((size_t)b << 11) + h * 256 + sg0 + sgl;
                Out[r * 256 + c] = oacc[mt][nt][i] + bias;
            }
        }
    }
}

// ---------------------------------------------------------------------------
extern "C" void kernel_launch(void* const* d_in, const int* in_sizes, int n_in,
                              void* d_out, int out_size, void* d_ws, size_t ws_size,
                              hipStream_t stream) {
    const float* query = (const float*)d_in[0];
    const float* key   = (const float*)d_in[1];
    const float* value = (const float*)d_in[2];
    const int*   mask  = (const int*)  d_in[3];
    const float* Wq = (const float*)d_in[4];  const float* bq = (const float*)d_in[5];
    const float* Wk = (const float*)d_in[6];  const float* bk = (const float*)d_in[7];
    const float* Wv = (const float*)d_in[8];  const float* bv = (const float*)d_in[9];
    const float* Wo = (const float*)d_in[10]; const float* bo = (const float*)d_in[11];

    // scratch in d_ws:
    char* ws = (char*)d_ws;
    bf16*  WoT = (bf16*)ws;                    // [256 c][2048 k] bf16, 1 MB
    bf16*  WqT = (bf16*)(ws + 1048576);        // [2048][256] bf16, 1 MB each
    bf16*  WkT = (bf16*)(ws + 2097152);
    bf16*  WvT = (bf16*)(ws + 3145728);
    float* bqp = (float*)(ws + 4194304);
    float* bkp = (float*)(ws + 4202496);
    float* bvp = (float*)(ws + 4210688);

    prep_kernel<<<515, 256, 0, stream>>>(
        Wq, Wk, Wv, bq, bk, bv, Wo, WqT, WkT, WvT, bqp, bkp, bvp, WoT);
    qkav_kernel<<<256, 512, 0, stream>>>(
        query, key, value, mask, WqT, WkT, WvT, bqp, bkp, bvp, WoT, bo,
        (float*)d_out);
}

// Round 8
// 260.634 us; speedup vs baseline: 1.3398x; 1.0081x over previous
//
#include <hip/hip_runtime.h>
#include <hip/hip_bf16.h>

typedef __hip_bfloat16 bf16;
typedef short bf16x8 __attribute__((ext_vector_type(8)));
typedef float f32x4 __attribute__((ext_vector_type(4)));

#define MFMA16(a,b,c) __builtin_amdgcn_mfma_f32_16x16x32_bf16(a,b,c,0,0,0)

// Non-draining barrier: drains this wave's LDS ops (cross-wave LDS deps are
// the only inter-wave communication in qkav), leaves global loads in flight
// across the barrier. __syncthreads() would emit s_waitcnt vmcnt(0) and kill
// the cross-barrier prefetch.
#define BARRIER() asm volatile("s_waitcnt lgkmcnt(0)\n\ts_barrier" ::: "memory")

__device__ __forceinline__ unsigned short f2us(float x){
    union{__hip_bfloat16 h; unsigned short u;} c; c.h = __float2bfloat16(x); return c.u;
}
__device__ __forceinline__ float us2f(unsigned short u){
    union{unsigned short u; __hip_bfloat16 h;} c; c.u = u; return __bfloat162float(c.h);
}
__device__ __forceinline__ uint4 pack8(float4 a, float4 b){
    union{unsigned short us[8]; uint4 v;} p;
    p.us[0]=f2us(a.x); p.us[1]=f2us(a.y); p.us[2]=f2us(a.z); p.us[3]=f2us(a.w);
    p.us[4]=f2us(b.x); p.us[5]=f2us(b.y); p.us[6]=f2us(b.z); p.us[7]=f2us(b.w);
    return p.v;
}

// ---------------------------------------------------------------------------
// prep: LDS-tiled transposes (unchanged).
// ---------------------------------------------------------------------------
__global__ __launch_bounds__(256) void prep_kernel(
    const float* __restrict__ Wq, const float* __restrict__ Wk,
    const float* __restrict__ Wv, const float* __restrict__ bq,
    const float* __restrict__ bk, const float* __restrict__ bv,
    const float* __restrict__ Wo,
    bf16* __restrict__ WqT, bf16* __restrict__ WkT, bf16* __restrict__ WvT,
    float* __restrict__ bqp, float* __restrict__ bkp, float* __restrict__ bvp,
    bf16* __restrict__ WoT)
{
    __shared__ float T[64][68];
    const int tid = threadIdx.x, bx = blockIdx.x;
    if (bx < 384) {
        const int mat = bx / 128, rem = bx % 128;
        const int c0 = (rem >> 5) * 64, n0 = (rem & 31) * 64;
        const float* W = (mat == 0) ? Wq : (mat == 1) ? Wk : Wv;
        bf16* WT = (mat == 0) ? WqT : (mat == 1) ? WkT : WvT;
        #pragma unroll
        for (int it = 0; it < 4; ++it) {
            int pp = tid + (it << 8);
            int cl = pp >> 4, n4 = (pp & 15) * 4;
            float4 f = *(const float4*)(W + (size_t)(c0 + cl) * 2048 + n0 + n4);
            T[cl][n4] = f.x; T[cl][n4+1] = f.y; T[cl][n4+2] = f.z; T[cl][n4+3] = f.w;
        }
        __syncthreads();
        const int h = n0 >> 8, d0 = n0 & 255;
        #pragma unroll
        for (int it = 0; it < 2; ++it) {
            int pp = tid + (it << 8);
            int j = pp >> 3, g = pp & 7;
            union{unsigned short us[8]; uint4 v;} pk;
            #pragma unroll
            for (int u = 0; u < 8; ++u) pk.us[u] = f2us(T[g*8+u][j]);
            *(uint4*)(WT + (size_t)((d0 + j) * 8 + h) * 256 + c0 + g * 8) = pk.v;
        }
    } else if (bx < 387) {
        const int mat = bx - 384;
        const float* src = (mat == 0) ? bq : (mat == 1) ? bk : bv;
        float* dst = (mat == 0) ? bqp : (mat == 1) ? bkp : bvp;
        for (int n = tid; n < 2048; n += 256)
            dst[(n & 255) * 8 + (n >> 8)] = src[n];
    } else {
        const int idx = bx - 387;
        const int k0 = (idx >> 2) * 64, c0 = (idx & 3) * 64;
        #pragma unroll
        for (int it = 0; it < 4; ++it) {
            int pp = tid + (it << 8);
            int kl = pp >> 4, c4 = (pp & 15) * 4;
            float4 f = *(const float4*)(Wo + (size_t)(k0 + kl) * 256 + c0 + c4);
            T[kl][c4] = f.x; T[kl][c4+1] = f.y; T[kl][c4+2] = f.z; T[kl][c4+3] = f.w;
        }
        __syncthreads();
        #pragma unroll
        for (int it = 0; it < 2; ++it) {
            int pp = tid + (it << 8);
            int j = pp >> 3, g = pp & 7;
            union{unsigned short us[8]; uint4 v;} pk;
            #pragma unroll
            for (int u = 0; u < 8; ++u) pk.us[u] = f2us(T[g*8+u][j]);
            *(uint4*)(WoT + (size_t)(c0 + j) * 2048 + k0 + g * 8) = pk.v;
        }
    }
}

// ---------------------------------------------------------------------------
// qkav v2: round-6 fused structure + non-draining barriers + depth-3
// cross-barrier register prefetch of weight B-frags + early-issued V loads.
// All cross-wave communication is LDS (QT/KT/RED/WLDS/VT/xS), so
// lgkmcnt(0)+s_barrier preserves correctness while vmcnt floats.
// ---------------------------------------------------------------------------
__global__ __launch_bounds__(512, 2) void qkav_kernel(
    const float* __restrict__ Qin, const float* __restrict__ Kin,
    const float* __restrict__ Vin, const int* __restrict__ mask,
    const bf16* __restrict__ WqT, const bf16* __restrict__ WkT,
    const bf16* __restrict__ WvT,
    const float* __restrict__ bqp, const float* __restrict__ bkp,
    const float* __restrict__ bvp,
    const bf16* __restrict__ WoT, const float* __restrict__ bo,
    float* __restrict__ Out)
{
    __shared__ __align__(16) char smem[147456];
    // phase 1 aliases
    char* const Xq = smem;
    char* const Xk = smem + 32768;
    char* const QT = smem + 65536;
    char* const KT = smem + 106496;
    float* const RED  = (float*)smem;            // [64][68] over Xq
    float* const WLDS = (float*)(smem + 106496); // [64][68] over KT (later)
    // phase 2 aliases
    char* const Xv  = smem;
    char* const VT0 = smem + 32768;
    char* const VT1 = smem + 50176;
    char* const xS0 = smem + 67584;
    char* const xS1 = smem + 83968;

    const int tid  = threadIdx.x;
    const int wid  = tid >> 6, lane = tid & 63;
    const int quad = lane >> 4, l15 = lane & 15;
    const int tok0 = blockIdx.x * 64;
    const int t6   = tid & 63, dg = tid >> 6;

    // ---- prologue prefetch: Cp=0 Ks=0..2 B-frags (in flight during staging)
    bf16x8 pbq[2][3], pbk[2][3];
    #pragma unroll
    for (int nt = 0; nt < 2; ++nt)
        #pragma unroll
        for (int Ks = 0; Ks < 3; ++Ks) {
            const size_t boff =
                (size_t)(wid * 32 + nt * 16 + l15) * 256 + Ks * 32 + quad * 8;
            pbq[nt][Ks] = *(const bf16x8*)(WqT + boff);
            pbk[nt][Ks] = *(const bf16x8*)(WkT + boff);
        }

    // ---------------- phase 1: Q/K projection + scores -----------------
    #pragma unroll
    for (int it = 0; it < 4; ++it) {
        int pp = tid + (it << 9);
        int row = pp >> 5, g = pp & 31;
        const float* s = Qin + (size_t)(tok0 + row) * 256 + g * 8;
        *(uint4*)(Xq + row * 512 + ((g ^ (row & 7)) << 4)) =
            pack8(*(const float4*)s, *(const float4*)(s + 4));
        s = Kin + (size_t)(tok0 + row) * 256 + g * 8;
        *(uint4*)(Xk + row * 512 + ((g ^ (row & 7)) << 4)) =
            pack8(*(const float4*)s, *(const float4*)(s + 4));
    }
    BARRIER();

    f32x4 sacc[4];
    #pragma unroll
    for (int p = 0; p < 4; ++p)
        #pragma unroll
        for (int i = 0; i < 4; ++i) sacc[p][i] = 0.f;

    for (int Cp = 0; Cp < 8; ++Cp) {
        f32x4 accq[4][2], acck[4][2];
        #pragma unroll
        for (int mt = 0; mt < 4; ++mt)
            #pragma unroll
            for (int nt = 0; nt < 2; ++nt)
                #pragma unroll
                for (int i = 0; i < 4; ++i) { accq[mt][nt][i] = 0.f; acck[mt][nt][i] = 0.f; }
        #pragma unroll
        for (int Ks = 0; Ks < 8; ++Ks) {
            bf16x8 bq[2], bk[2];
            #pragma unroll
            for (int nt = 0; nt < 2; ++nt) {
                if (Ks < 3) {
                    bq[nt] = pbq[nt][Ks];
                    bk[nt] = pbk[nt][Ks];
                } else {
                    const size_t boff =
                        (size_t)(Cp * 256 + wid * 32 + nt * 16 + l15) * 256 + Ks * 32 + quad * 8;
                    bq[nt] = *(const bf16x8*)(WqT + boff);
                    bk[nt] = *(const bf16x8*)(WkT + boff);
                }
            }
            #pragma unroll
            for (int mt = 0; mt < 4; ++mt) {
                int row = mt * 16 + l15;
                int G = (Ks * 4 + quad) ^ (row & 7);
                bf16x8 aq = *(const bf16x8*)(Xq + row * 512 + (G << 4));
                bf16x8 ak = *(const bf16x8*)(Xk + row * 512 + (G << 4));
                #pragma unroll
                for (int nt = 0; nt < 2; ++nt) {
                    accq[mt][nt] = MFMA16(aq, bq[nt], accq[mt][nt]);
                    acck[mt][nt] = MFMA16(ak, bk[nt], acck[mt][nt]);
                }
            }
        }
        // issue next-Cp prefetch NOW: in flight across pack + 2 barriers + score
        if (Cp < 7) {
            #pragma unroll
            for (int nt = 0; nt < 2; ++nt)
                #pragma unroll
                for (int Ks = 0; Ks < 3; ++Ks) {
                    const size_t boff =
                        (size_t)((Cp + 1) * 256 + wid * 32 + nt * 16 + l15) * 256 + Ks * 32 + quad * 8;
                    pbq[nt][Ks] = *(const bf16x8*)(WqT + boff);
                    pbk[nt][Ks] = *(const bf16x8*)(WkT + boff);
                }
        }
        #pragma unroll
        for (int nt = 0; nt < 2; ++nt) {
            const int p2 = wid * 32 + nt * 16 + l15;
            const int rowoff = p2 * 160 + ((p2 >> 6) & 3) * 8;
            const float biq = bqp[Cp * 256 + p2];
            const float bik = bkp[Cp * 256 + p2];
            #pragma unroll
            for (int mt = 0; mt < 4; ++mt) {
                int t0 = mt * 16 + quad * 4;
                union{unsigned short us[4]; uint2 v;} pq, pk;
                #pragma unroll
                for (int i = 0; i < 4; ++i) {
                    pq.us[i] = f2us(accq[mt][nt][i] + biq);
                    pk.us[i] = f2us(acck[mt][nt][i] + bik);
                }
                *(uint2*)(QT + rowoff + t0 * 2) = pq.v;
                *(uint2*)(KT + rowoff + t0 * 2) = pk.v;
            }
        }
        BARRIER();
        #pragma unroll
        for (int pp2 = 0; pp2 < 4; ++pp2) {
            int tq = 2 * (wid * 4 + pp2) + (l15 >> 3);
            union{unsigned short us[8]; bf16x8 v;} Aq, Bk;
            #pragma unroll
            for (int j = 0; j < 8; ++j) {
                int p2 = (quad * 8 + j) * 8 + (l15 & 7);
                int off = p2 * 160 + ((p2 >> 6) & 3) * 8 + tq * 2;
                Aq.us[j] = *(const unsigned short*)(QT + off);
                Bk.us[j] = *(const unsigned short*)(KT + off);
            }
            sacc[pp2] = MFMA16(Aq.v, Bk.v, sacc[pp2]);
        }
        BARRIER();
    }

    // early-issue V input loads + chunk-0 WvT prefetch: complete under
    // diag extraction + softmax; consumed after the softmax barrier.
    float4 xvA[4], xvB[4];
    #pragma unroll
    for (int it = 0; it < 4; ++it) {
        int pp = tid + (it << 9);
        int row = pp >> 5, g = pp & 31;
        const float* s = Vin + (size_t)(tok0 + row) * 256 + g * 8;
        xvA[it] = *(const float4*)s;
        xvB[it] = *(const float4*)(s + 4);
    }
    const int pll = wid * 16 + l15;
    bf16x8 pv[3];
    #pragma unroll
    for (int Ks = 0; Ks < 3; ++Ks)
        pv[Ks] = *(const bf16x8*)(WvT + (size_t)pll * 256 + Ks * 32 + quad * 8);

    // diagonal extraction -> RED[t][h*8+g]  (Xq dead, KT dead)
    if ((quad >> 1) == (l15 >> 3)) {
        #pragma unroll
        for (int pp2 = 0; pp2 < 4; ++pp2) {
            int tl = (wid * 4 + pp2) * 2 + (l15 >> 3);
            #pragma unroll
            for (int i = 0; i < 4; ++i)
                RED[tl * 68 + ((quad & 1) * 4 + i) * 8 + (l15 & 7)] = sacc[pp2][i];
        }
    }
    BARRIER();
    // softmax: thread (tl, h) -> WLDS
    {
        const int tl = tid >> 3, hh = tid & 7;
        const int mk = mask[tok0 + tl];
        const float* r = RED + tl * 68 + hh * 8;
        float m = r[0];
        #pragma unroll
        for (int g = 1; g < 8; ++g) m = fmaxf(m, r[g]);
        float e[8], sum = 0.f;
        #pragma unroll
        for (int g = 0; g < 8; ++g) { e[g] = __expf((r[g] - m) * 0.0625f); sum += e[g]; }
        float inv = 1.f / sum;
        float o[8];
        #pragma unroll
        for (int g = 0; g < 8; ++g) o[g] = mk ? e[g] * inv : 0.125f;
        float* wp = WLDS + tl * 68 + hh * 8;
        *(float4*)wp = make_float4(o[0], o[1], o[2], o[3]);
        *(float4*)(wp + 4) = make_float4(o[4], o[5], o[6], o[7]);
    }
    BARRIER();

    // ---------------- phase 2: V projection + wsum + out-proj ----------
    float wv[64];
    {
        const float* wl = WLDS + t6 * 68;
        #pragma unroll
        for (int i = 0; i < 16; ++i) {
            float4 f = *(const float4*)(wl + i * 4);
            wv[i*4] = f.x; wv[i*4+1] = f.y; wv[i*4+2] = f.z; wv[i*4+3] = f.w;
        }
    }
    #pragma unroll
    for (int it = 0; it < 4; ++it) {
        int pp = tid + (it << 9);
        int row = pp >> 5, g = pp & 31;
        *(uint4*)(Xv + row * 512 + ((g ^ (row & 7)) << 4)) = pack8(xvA[it], xvB[it]);
    }
    BARRIER();

    f32x4 oacc[4][2];
    #pragma unroll
    for (int mt = 0; mt < 4; ++mt)
        #pragma unroll
        for (int nt = 0; nt < 2; ++nt)
            #pragma unroll
            for (int i = 0; i < 4; ++i) oacc[mt][nt][i] = 0.f;

    for (int p = 0; p < 18; ++p) {
        char* const VTw = (p & 1) ? VT1 : VT0;
        char* const VTr = (p & 1) ? VT0 : VT1;
        char* const xSw = (p & 1) ? xS0 : xS1;
        char* const xSr = (p & 1) ? xS1 : xS0;

        // --- stream 1: v-proj for chunk C = p ---
        if (p < 16) {
            const int C = p;
            f32x4 acc[4];
            #pragma unroll
            for (int mt = 0; mt < 4; ++mt)
                #pragma unroll
                for (int i = 0; i < 4; ++i) acc[mt][i] = 0.f;
            #pragma unroll
            for (int Ks = 0; Ks < 8; ++Ks) {
                bf16x8 b;
                if (Ks < 3) b = pv[Ks];
                else b = *(const bf16x8*)(WvT + (size_t)(C * 128 + pll) * 256 + Ks * 32 + quad * 8);
                #pragma unroll
                for (int mt = 0; mt < 4; ++mt) {
                    int row = mt * 16 + l15;
                    int G = (Ks * 4 + quad) ^ (row & 7);
                    bf16x8 a = *(const bf16x8*)(Xv + row * 512 + (G << 4));
                    acc[mt] = MFMA16(a, b, acc[mt]);
                }
            }
            // prefetch next chunk's first 3 WvT frags across the barrier
            if (C < 15) {
                #pragma unroll
                for (int Ks = 0; Ks < 3; ++Ks)
                    pv[Ks] = *(const bf16x8*)(WvT + (size_t)((C + 1) * 128 + pll) * 256 + Ks * 32 + quad * 8);
            }
            const float biv = bvp[C * 128 + pll];
            #pragma unroll
            for (int mt = 0; mt < 4; ++mt) {
                int t0 = mt * 16 + quad * 4;
                union{unsigned short us[4]; uint2 v;} pk;
                #pragma unroll
                for (int i = 0; i < 4; ++i) pk.us[i] = f2us(acc[mt][i] + biv);
                *(uint2*)(VTw + pll * 136 + t0 * 2) = pk.v;
            }
        }

        // --- stream 2: weighted sum for chunk C = p-1 (VALU pipe) ---
        if (p >= 1 && p <= 16) {
            #pragma unroll
            for (int dd = 0; dd < 2; ++dd) {
                int d = dg * 2 + dd;
                float vv[8];
                #pragma unroll
                for (int g = 0; g < 8; ++g)
                    vv[g] = us2f(*(const unsigned short*)(VTr + (d * 8 + g) * 136 + t6 * 2));
                #pragma unroll
                for (int h = 0; h < 8; ++h) {
                    float x = 0.f;
                    #pragma unroll
                    for (int g = 0; g < 8; ++g) x = fmaf(wv[h * 8 + g], vv[g], x);
                    int u = (h * 2 + (d >> 3)) ^ (t6 & 15);
                    *(unsigned short*)(xSw + t6 * 256 + u * 16 + (d & 7) * 2) = f2us(x);
                }
            }
        }

        // --- stream 3: out-proj accumulate for chunk C = p-2 ---
        // (WoT loads sit inside the interval with no barrier above them, so
        // the compiler can hoist them to interval start — already overlapped.)
        if (p >= 2) {
            const int C = p - 2;
            #pragma unroll
            for (int m = 0; m < 4; ++m) {
                const int j  = 2 * m + (quad >> 1);
                const int k0 = j * 256 + C * 16 + (quad & 1) * 8;
                bf16x8 bfr[2];
                #pragma unroll
                for (int nt = 0; nt < 2; ++nt) {
                    int c = wid * 32 + nt * 16 + l15;
                    bfr[nt] = *(const bf16x8*)(WoT + (size_t)c * 2048 + k0);
                }
                #pragma unroll
                for (int mt = 0; mt < 4; ++mt) {
                    int h = mt * 2 + (l15 >> 3);
                    int t = (l15 & 7) * 8 + j;
                    int u = (h * 2 + (quad & 1)) ^ (t & 15);
                    bf16x8 afr = *(const bf16x8*)(xSr + t * 256 + u * 16);
                    #pragma unroll
                    for (int nt = 0; nt < 2; ++nt)
                        oacc[mt][nt] = MFMA16(afr, bfr[nt], oacc[mt][nt]);
                }
            }
        }

        BARRIER();
    }

    // epilogue: bias + direct Out write (reference's transpose-reshape rows)
    const int b = tok0 >> 11, sg0 = (tok0 & 2047) >> 3;
    #pragma unroll
    for (int nt = 0; nt < 2; ++nt) {
        int c = wid * 32 + nt * 16 + l15;
        float bias = bo[c];
        #pragma unroll
        for (int mt = 0; mt < 4; ++mt) {
            #pragma unroll
            for (int i = 0; i < 4; ++i) {
                int rr = mt * 16 + quad * 4 + i;
                int h = rr >> 3, sgl = rr & 7;
                size_t r = ((size_t)b << 11) + h * 256 + sg0 + sgl;
                Out[r * 256 + c] = oacc[mt][nt][i] + bias;
            }
        }
    }
}

// ---------------------------------------------------------------------------
extern "C" void kernel_launch(void* const* d_in, const int* in_sizes, int n_in,
                              void* d_out, int out_size, void* d_ws, size_t ws_size,
                              hipStream_t stream) {
    const float* query = (const float*)d_in[0];
    const float* key   = (const float*)d_in[1];
    const float* value = (const float*)d_in[2];
    const int*   mask  = (const int*)  d_in[3];
    const float* Wq = (const float*)d_in[4];  const float* bq = (const float*)d_in[5];
    const float* Wk = (const float*)d_in[6];  const float* bk = (const float*)d_in[7];
    const float* Wv = (const float*)d_in[8];  const float* bv = (const float*)d_in[9];
    const float* Wo = (const float*)d_in[10]; const float* bo = (const float*)d_in[11];

    // scratch in d_ws:
    char* ws = (char*)d_ws;
    bf16*  WoT = (bf16*)ws;                    // [256 c][2048 k] bf16, 1 MB
    bf16*  WqT = (bf16*)(ws + 1048576);        // [2048][256] bf16, 1 MB each
    bf16*  WkT = (bf16*)(ws + 2097152);
    bf16*  WvT = (bf16*)(ws + 3145728);
    float* bqp = (float*)(ws + 4194304);
    float* bkp = (float*)(ws + 4202496);
    float* bvp = (float*)(ws + 4210688);

    prep_kernel<<<515, 256, 0, stream>>>(
        Wq, Wk, Wv, bq, bk, bv, Wo, WqT, WkT, WvT, bqp, bkp, bvp, WoT);
    qkav_kernel<<<256, 512, 0, stream>>>(
        query, key, value, mask, WqT, WkT, WvT, bqp, bkp, bvp, WoT, bo,
        (float*)d_out);
}